// Round 12
// baseline (410.616 us; speedup 1.0000x reference)
//
#include <hip/hip_runtime.h>
#include <math.h>

#define B_TOT   16384
#define SB      6              // 6 samples/block: conv1-src tasks = 60 <= 64 lanes (binding)
#define TPB     512

// ---- per-sample LDS layout (floats)
#define SSTRIDE 1652
#define OFF_H   0              // 11*36 = 396, lives whole kernel
#define OFF_EA  396            // 68
#define OFF_H1  464            // 396, post1 out -> conv_T2 in
#define OFF_AGG 860            // 792-region: TD/TS during conv; AGG after fused store
#define OFF_TD  OFF_AGG
#define OFF_TS  (OFF_AGG + 396)
#define OFF_A4  600            // node4 agg offset within AGG region
#define OFF_A10 640            // node10 agg offset within AGG region
#define WLDS    (SB * SSTRIDE) // 9912

// ---- LDS weight-table (wl) layout (small tables only; WC1 stays global/L1)
#define LW_B4   0              // node4 post1 bias incl sigma0*std-colsum (32)
#define LW_H1C  32             // const h1 row for nodes 0..2 (32) [table slot, unused]
#define LW_V1C1 64             // class1 post2 vector (96)
#define LW_V10  160            // node10 post2 vector (128)
#define LW_V4   288            // node4 post2 vector (32)
#define LW_C42  320            // node4 post2 sigma0 const (1) + 3 pad
#define LW_TSC  324            // const conv2 src-transform row (nodes 0..2 share it) (32)
#define LW_BP1  356            // b_post1 row (32)
#define LTAB    388

// ---- EAT region: per-sample precomputed ea@Wpre[64:68] terms, 17 edges x 32 f.
// stride 548 (=544+4): s-term rotates banks so float4 reads spread across groups.
#define EATSTRIDE 548
#define OFF_EAT  (WLDS + LTAB)                 // 10300
#define OFF_PACC (OFF_EAT + SB * EATSTRIDE)    // 13588
#define LDS_FLOATS (OFF_PACC + 16)             // 13604 floats = 54416 B -> 2 blocks/CU
#define AVG_LOG 0.9976091242438673f

// ---- ws per-intervention folded table
#define G_WC1  0               // class1 post1 [96][32] (global, L1-hot, 6 waves read)
#define G_W10  3072            // node10 post1 [128][32] (wave 7 only)
#define G_W4   7168            // node4 post1 [32][32]  (wave 6 only)
#define G_SM   8192            // small tail (356) staged to wl[0..356)
#define WTAB   8548
#define WS_TAB 64              // ws: [0..39] gacc, [40..42] const-node sigmoid

__constant__ int C_ESRC[17] = {0,0,1,1,2,0,3,4,5,6,7,2,8,3,6,9,1};
__constant__ int C1EA[6] = {0,3,5,7,9,11};     // first in-edge of deg-2 nodes
__constant__ int C1EB[6] = {2,4,6,8,10,12};    // second in-edge
__constant__ int C1N[6]  = {3,5,6,7,8,9};      // deg-2 node ids

#define FMA16(a, wb, u) do { \
    float4 w0_ = *(const float4*)(wb); \
    float4 w1_ = *(const float4*)((wb) + 32); \
    float4 w2_ = *(const float4*)((wb) + 64); \
    float4 w3_ = *(const float4*)((wb) + 96); \
    u.x = fmaf(a.x, w0_.x, u.x); u.y = fmaf(a.x, w0_.y, u.y); u.z = fmaf(a.x, w0_.z, u.z); u.w = fmaf(a.x, w0_.w, u.w); \
    u.x = fmaf(a.y, w1_.x, u.x); u.y = fmaf(a.y, w1_.y, u.y); u.z = fmaf(a.y, w1_.z, u.z); u.w = fmaf(a.y, w1_.w, u.w); \
    u.x = fmaf(a.z, w2_.x, u.x); u.y = fmaf(a.z, w2_.y, u.y); u.z = fmaf(a.z, w2_.z, u.z); u.w = fmaf(a.z, w2_.w, u.w); \
    u.x = fmaf(a.w, w3_.x, u.x); u.y = fmaf(a.w, w3_.y, u.y); u.z = fmaf(a.w, w3_.z, u.z); u.w = fmaf(a.w, w3_.w, u.w); \
} while (0)

// message for edge e_: m = relu(base + TS[src] + EAT[e])  -- ea@W precomputed in LDS
#define MSG(e_, m_) do { \
    const float4 ts_ = *(const float4*)(S + OFF_TS + C_ESRC[(e_)] * 36 + f); \
    const float4 ea_ = *(const float4*)(EAT_s + (e_) * 32 + f); \
    m_.x = fmaxf(base.x + ts_.x + ea_.x, 0.f); \
    m_.y = fmaxf(base.y + ts_.y + ea_.y, 0.f); \
    m_.z = fmaxf(base.z + ts_.z + ea_.z, 0.f); \
    m_.w = fmaxf(base.w + ts_.w + ea_.w, 0.f); \
} while (0)

static __device__ __forceinline__ float coef3(const float* __restrict__ W1, int r, int fcol, float amp, float att)
{
    return W1[r * 32 + fcol] + amp * W1[(128 + r) * 32 + fcol] + att * W1[(256 + r) * 32 + fcol];
}
static __device__ __forceinline__ float coef3s(const float* __restrict__ W2, int r, float amp, float att)
{
    return W2[r] + amp * W2[128 + r] + att * W2[256 + r];
}

// ---- one-shot fold: amp/att per degree class + graph-structure identities
extern "C" __global__ void pna_fold(const float* __restrict__ W_post1, const float* __restrict__ b_post1,
                                    const float* __restrict__ W_post2, const float* __restrict__ b_post2,
                                    const float* __restrict__ W_pre2,  float* __restrict__ ws)
{
    const int t0 = blockIdx.x * blockDim.x + threadIdx.x;
    const int NT = gridDim.x * blockDim.x;
    const float l1 = log1pf(1.f), l2 = log1pf(2.f), l4 = log1pf(4.f);
    const float amp1 = l1 / AVG_LOG, att1 = AVG_LOG / l1;
    const float amp2 = l2 / AVG_LOG, att2 = AVG_LOG / l2;
    const float amp4 = l4 / AVG_LOG, att4 = AVG_LOG / l4;
    const float SIG0 = 0.0031622776601683794f;   // sqrt(1e-5)

    for (int idx = t0; idx < 3 * WTAB; idx += NT) {
        const int i = idx / WTAB, off = idx % WTAB;
        const float* W1 = W_post1 + i * 384 * 32;
        const float* W2 = W_post2 + i * 384;
        float val = 0.f;
        if (off < 3072) {                                   // WC1: deg-2 fold (mx = 2*mean - mn)
            const int j = off >> 5, fcol = off & 31, sub = j >> 5, jj = j & 31;
            if (sub == 0)      val = coef3(W1, jj, fcol, amp2, att2) + 2.f * coef3(W1, 64 + jj, fcol, amp2, att2);
            else if (sub == 1) val = coef3(W1, 32 + jj, fcol, amp2, att2) - coef3(W1, 64 + jj, fcol, amp2, att2);
            else               val = coef3(W1, 96 + jj, fcol, amp2, att2);
        } else if (off < 7168) {                            // W10: full [mean|mn|mx|std] rows
            const int rr = off - 3072;
            val = coef3(W1, rr >> 5, rr & 31, amp4, att4);
        } else if (off < 8192) {                            // W4: Wm+Wmn+Wmx fold
            const int rr = off - 7168, jj = rr >> 5, fcol = rr & 31;
            val = coef3(W1, jj, fcol, amp1, att1) + coef3(W1, 32 + jj, fcol, amp1, att1)
                + coef3(W1, 64 + jj, fcol, amp1, att1);
        } else if (off < 8224) {                            // B4
            const int fcol = off - 8192;
            float ssum = 0.f;
            for (int jj = 0; jj < 32; ++jj) ssum += coef3(W1, 96 + jj, fcol, amp1, att1);
            val = b_post1[i * 32 + fcol] + SIG0 * ssum;
        } else if (off < 8256) {                            // H1C (const rows, nodes 0..2)
            const int fcol = off - 8224;
            float ssum = 0.f;
            for (int jj = 0; jj < 32; ++jj) ssum += coef3(W1, 96 + jj, fcol, amp1, att1);
            val = fmaxf(b_post1[i * 32 + fcol] + SIG0 * ssum, 0.f);
        } else if (off < 8352) {                            // V1C1
            const int j = off - 8256, sub = j >> 5, jj = j & 31;
            if (sub == 0)      val = coef3s(W2, jj, amp2, att2) + 2.f * coef3s(W2, 64 + jj, amp2, att2);
            else if (sub == 1) val = coef3s(W2, 32 + jj, amp2, att2) - coef3s(W2, 64 + jj, amp2, att2);
            else               val = coef3s(W2, 96 + jj, amp2, att2);
        } else if (off < 8480) {                            // V10
            val = coef3s(W2, off - 8352, amp4, att4);
        } else if (off < 8512) {                            // V4
            const int jj = off - 8480;
            val = coef3s(W2, jj, amp1, att1) + coef3s(W2, 32 + jj, amp1, att1) + coef3s(W2, 64 + jj, amp1, att1);
        } else if (off == 8512) {                           // C42
            float ssum = 0.f;
            for (int jj = 0; jj < 32; ++jj) ssum += coef3s(W2, 96 + jj, amp1, att1);
            val = SIG0 * ssum;
        } else if (off >= 8516 && off < 8548) {             // TSC: conv2 src-transform of const h1 (nodes 0..2)
            const int fcol = off - 8516;
            const float* Wp2 = W_pre2 + i * 2176;
            float acc = 0.f;
            for (int k = 0; k < 32; ++k) {
                float ssum = 0.f;
                for (int jj = 0; jj < 32; ++jj) ssum += coef3(W1, 96 + jj, k, amp1, att1);
                const float h1c = fmaxf(b_post1[i * 32 + k] + SIG0 * ssum, 0.f);
                acc = fmaf(h1c, Wp2[(32 + k) * 32 + fcol], acc);
            }
            val = acc;
        }
        ws[WS_TAB + idx] = val;
    }
    if (t0 < 40) ws[t0] = 0.f;                              // gacc zero
    if (t0 >= 40 && t0 < 43) {                              // const-node sigmoid per intervention
        const int i = t0 - 40;
        const float* W2 = W_post2 + i * 384;
        float ssum = 0.f;
        for (int jj = 0; jj < 32; ++jj) ssum += coef3s(W2, 96 + jj, amp1, att1);
        ws[40 + i] = 1.f / (1.f + expf(-(b_post2[i] + SIG0 * ssum)));
    }
}

// ---- per-node transform + EAT precompute. dst waves (ty=0): nodes 3..10 (8/sample).
// src waves (ty=1): conv1 nodes 0..9 (10); conv2 nodes 3..9 (7) + const TS copy for 0..2.
// Appendix (all threads): EAT[s][e][f] = ea[s][e] @ Wp[64:68] (weights straight from global).
template<int PASS>
static __device__ __forceinline__ void conv_T(float* lds, const float* wl, int nsamp, int w, int lane,
                                              int hoff, const float* __restrict__ Wp,
                                              const float* __restrict__ bp)
{
    const int ty = w & 1;
    const int f0 = (w >> 1) * 8;
    int s, n, tasks;
    if (ty == 0)            { tasks = nsamp * 8;  s = lane >> 3;  n = 3 + (lane & 7); }
    else if (PASS == 0)     { tasks = nsamp * 10; s = lane / 10;  n = lane % 10; }
    else                    { tasks = nsamp * 7;  s = lane / 7;   n = 3 + lane % 7; }
    const bool act = lane < tasks;
    if (!act) { s = 0; n = 3; }
    const float* Hrow = lds + s * SSTRIDE + hoff + n * 36;
    const float* wbase = Wp + ty * 32 * 32 + f0;        // wave-uniform -> s_load
    float acc[8];
#pragma unroll
    for (int f = 0; f < 8; f++) acc[f] = ty ? 0.f : bp[f0 + f];
#pragma unroll
    for (int kq = 0; kq < 8; kq++) {
        float4 a = *(const float4*)(Hrow + kq * 4);
#pragma unroll
        for (int kk = 0; kk < 4; kk++) {
            float av = (kk == 0) ? a.x : (kk == 1) ? a.y : (kk == 2) ? a.z : a.w;
            const float* wr = wbase + (kq * 4 + kk) * 32;
#pragma unroll
            for (int f = 0; f < 8; f++) acc[f] = fmaf(av, wr[f], acc[f]);
        }
    }
    float* T = lds + s * SSTRIDE + (ty ? OFF_TS : OFF_TD) + n * 36 + f0;
    if (act) {
        *(float4*)(T + 0) = make_float4(acc[0], acc[1], acc[2], acc[3]);
        *(float4*)(T + 4) = make_float4(acc[4], acc[5], acc[6], acc[7]);
    }
    if (PASS == 1 && ty == 1) {                         // const TS rows (nodes 0..2 share one vector)
        if (lane < nsamp * 3) {
            const int cs = lane / 3, cn = lane % 3;
            float* Tc = lds + cs * SSTRIDE + OFF_TS + cn * 36 + f0;
            *(float4*)(Tc)     = *(const float4*)(wl + LW_TSC + f0);
            *(float4*)(Tc + 4) = *(const float4*)(wl + LW_TSC + f0 + 4);
        }
    }
    // EAT appendix: tasks = nsamp*17*8 (e, f-quad); weights from global rows 64..67 (L1-hot)
    const int tid2 = (w << 6) | lane;
    for (int t = tid2; t < nsamp * 136; t += TPB) {
        const int s2 = t / 136, r2 = t - s2 * 136, e2 = r2 >> 3, fo = (r2 & 7) * 4;
        const float4 ev = *(const float4*)(lds + s2 * SSTRIDE + OFF_EA + e2 * 4);
        const float4 wa = *(const float4*)(Wp + 2048 + fo);
        const float4 wb = *(const float4*)(Wp + 2080 + fo);
        const float4 wc = *(const float4*)(Wp + 2112 + fo);
        const float4 wd = *(const float4*)(Wp + 2144 + fo);
        float4 t4;
        t4.x = ev.x * wa.x; t4.y = ev.x * wa.y; t4.z = ev.x * wa.z; t4.w = ev.x * wa.w;
        t4.x = fmaf(ev.y, wb.x, t4.x); t4.y = fmaf(ev.y, wb.y, t4.y);
        t4.z = fmaf(ev.y, wb.z, t4.z); t4.w = fmaf(ev.y, wb.w, t4.w);
        t4.x = fmaf(ev.z, wc.x, t4.x); t4.y = fmaf(ev.z, wc.y, t4.y);
        t4.z = fmaf(ev.z, wc.z, t4.z); t4.w = fmaf(ev.z, wc.w, t4.w);
        t4.x = fmaf(ev.w, wd.x, t4.x); t4.y = fmaf(ev.w, wd.y, t4.y);
        t4.z = fmaf(ev.w, wd.z, t4.z); t4.w = fmaf(ev.w, wd.w, t4.w);
        *(float4*)(lds + OFF_EAT + s2 * EATSTRIDE + e2 * 32 + fo) = t4;
    }
}

// ---- fused message+aggregate, EAT-based (no weight regs). wave = node class.
// CONV2=0: compute agg in regs, barrier, store AGG. CONV2=1: dot with folded post2
// vector, shfl-reduce, sigmoid, LDS-atomic pacc.
template<int CONV2>
static __device__ __forceinline__ void fused_conv(float* lds, const float* wl, int nsamp,
                                                  int w, int lane, float b2, float* pacc)
{
    const bool act = lane < nsamp * 8;
    const int l = act ? lane : 0;
    const int s = l >> 3, q = l & 7, f = q * 4;
    float* S = lds + s * SSTRIDE;
    const float* EAT_s = lds + OFF_EAT + s * EATSTRIDE;

    float4 r0 = make_float4(0.f,0.f,0.f,0.f), r1 = r0, r2 = r0, r3 = r0;
    float u = 0.f;

    if (w < 6) {                                           // deg-2 node C1N[w]
        const int n = C1N[w];
        float4 base = *(const float4*)(S + OFF_TD + n * 36 + f);
        float4 ma, mb;
        MSG(C1EA[w], ma);
        MSG(C1EB[w], mb);
        r0.x = (ma.x + mb.x) * 0.5f; r0.y = (ma.y + mb.y) * 0.5f;
        r0.z = (ma.z + mb.z) * 0.5f; r0.w = (ma.w + mb.w) * 0.5f;
        r1.x = fminf(ma.x, mb.x); r1.y = fminf(ma.y, mb.y);
        r1.z = fminf(ma.z, mb.z); r1.w = fminf(ma.w, mb.w);
        float4 msq;
        msq.x = fmaf(mb.x, mb.x, ma.x * ma.x) * 0.5f;
        msq.y = fmaf(mb.y, mb.y, ma.y * ma.y) * 0.5f;
        msq.z = fmaf(mb.z, mb.z, ma.z * ma.z) * 0.5f;
        msq.w = fmaf(mb.w, mb.w, ma.w * ma.w) * 0.5f;
        r2.x = sqrtf(fmaxf(msq.x - r0.x * r0.x, 0.f) + 1e-5f);
        r2.y = sqrtf(fmaxf(msq.y - r0.y * r0.y, 0.f) + 1e-5f);
        r2.z = sqrtf(fmaxf(msq.z - r0.z * r0.z, 0.f) + 1e-5f);
        r2.w = sqrtf(fmaxf(msq.w - r0.w * r0.w, 0.f) + 1e-5f);
        if (CONV2) {
            const float* V = wl + LW_V1C1 + f;
            const float4 v0 = *(const float4*)(V);
            const float4 v1 = *(const float4*)(V + 32);
            const float4 v2 = *(const float4*)(V + 64);
            u = fmaf(r0.x, v0.x, fmaf(r0.y, v0.y, fmaf(r0.z, v0.z, r0.w * v0.w)));
            u = fmaf(r1.x, v1.x, fmaf(r1.y, v1.y, fmaf(r1.z, v1.z, fmaf(r1.w, v1.w, u))));
            u = fmaf(r2.x, v2.x, fmaf(r2.y, v2.y, fmaf(r2.z, v2.z, fmaf(r2.w, v2.w, u))));
        }
    } else if (w == 6) {                                   // node4 (deg-1): agg = message
        float4 base = *(const float4*)(S + OFF_TD + 4 * 36 + f);
        float4 m;
        MSG(1, m);
        r0 = m;
        if (CONV2) {
            const float4 v0 = *(const float4*)(wl + LW_V4 + f);
            u = fmaf(m.x, v0.x, fmaf(m.y, v0.y, fmaf(m.z, v0.z, m.w * v0.w)));
        }
    } else {                                               // node10 (deg-4), edges 13..16
        float4 base = *(const float4*)(S + OFF_TD + 10 * 36 + f);
        float4 sum = make_float4(0.f,0.f,0.f,0.f), sq = sum;
        float4 mn = make_float4(1e30f,1e30f,1e30f,1e30f);
        float4 mx = make_float4(-1e30f,-1e30f,-1e30f,-1e30f);
#pragma unroll
        for (int e = 13; e <= 16; ++e) {
            float4 m;
            MSG(e, m);
            sum.x += m.x; sum.y += m.y; sum.z += m.z; sum.w += m.w;
            sq.x = fmaf(m.x, m.x, sq.x); sq.y = fmaf(m.y, m.y, sq.y);
            sq.z = fmaf(m.z, m.z, sq.z); sq.w = fmaf(m.w, m.w, sq.w);
            mn.x = fminf(mn.x, m.x); mn.y = fminf(mn.y, m.y); mn.z = fminf(mn.z, m.z); mn.w = fminf(mn.w, m.w);
            mx.x = fmaxf(mx.x, m.x); mx.y = fmaxf(mx.y, m.y); mx.z = fmaxf(mx.z, m.z); mx.w = fmaxf(mx.w, m.w);
        }
        r0.x = sum.x * 0.25f; r0.y = sum.y * 0.25f; r0.z = sum.z * 0.25f; r0.w = sum.w * 0.25f;
        r1 = mn; r2 = mx;
        float4 msq = make_float4(sq.x * 0.25f, sq.y * 0.25f, sq.z * 0.25f, sq.w * 0.25f);
        r3.x = sqrtf(fmaxf(msq.x - r0.x * r0.x, 0.f) + 1e-5f);
        r3.y = sqrtf(fmaxf(msq.y - r0.y * r0.y, 0.f) + 1e-5f);
        r3.z = sqrtf(fmaxf(msq.z - r0.z * r0.z, 0.f) + 1e-5f);
        r3.w = sqrtf(fmaxf(msq.w - r0.w * r0.w, 0.f) + 1e-5f);
        if (CONV2) {
            const float* V = wl + LW_V10 + f;
            const float4 v0 = *(const float4*)(V);
            const float4 v1 = *(const float4*)(V + 32);
            const float4 v2 = *(const float4*)(V + 64);
            const float4 v3 = *(const float4*)(V + 96);
            u = fmaf(r0.x, v0.x, fmaf(r0.y, v0.y, fmaf(r0.z, v0.z, r0.w * v0.w)));
            u = fmaf(r1.x, v1.x, fmaf(r1.y, v1.y, fmaf(r1.z, v1.z, fmaf(r1.w, v1.w, u))));
            u = fmaf(r2.x, v2.x, fmaf(r2.y, v2.y, fmaf(r2.z, v2.z, fmaf(r2.w, v2.w, u))));
            u = fmaf(r3.x, v3.x, fmaf(r3.y, v3.y, fmaf(r3.z, v3.z, fmaf(r3.w, v3.w, u))));
        }
    }

    if (!CONV2) {
        __syncthreads();                                   // all reads of TD/TS done before AGG overwrite
        if (act) {
            if (w < 6) {
                float* A = S + OFF_AGG + w * 100;
                *(float4*)(A + f) = r0; *(float4*)(A + 32 + f) = r1; *(float4*)(A + 64 + f) = r2;
            } else if (w == 6) {
                *(float4*)(S + OFF_AGG + OFF_A4 + f) = r0;
            } else {
                float* A = S + OFF_AGG + OFF_A10;
                *(float4*)(A + f) = r0; *(float4*)(A + 32 + f) = r1;
                *(float4*)(A + 64 + f) = r2; *(float4*)(A + 96 + f) = r3;
            }
        }
    } else {
        u += __shfl_xor(u, 1);
        u += __shfl_xor(u, 2);
        u += __shfl_xor(u, 4);
        if (act && q == 0) {
            const float extra = (w == 6) ? wl[LW_C42] : 0.f;
            const int node = (w < 6) ? C1N[w] : (w == 6 ? 4 : 10);
            const float p = 1.f / (1.f + expf(-(u + b2 + extra)));
            atomicAdd(pacc + node, p);
        }
    }
}

// ---- post1: waves 0..5 class1, wave 6 node4, wave 7 node10 — all weights from
// global folded table (L1-hot; 8 distinct float4s per load instruction).
static __device__ __forceinline__ void post1_new(float* lds, const float* wl, int nsamp, int w, int lane,
                                                 const float* __restrict__ tabg)
{
    const bool act = lane < nsamp * 8;
    const int l = act ? lane : 0;
    const int s = l >> 3, q = l & 7;
    if (w < 6) {
        const float* A = lds + s * SSTRIDE + OFF_AGG + w * 100;
        const float* W = tabg + G_WC1 + q * 4;
        float4 u = make_float4(0.f,0.f,0.f,0.f);
#pragma unroll 2
        for (int jq = 0; jq < 24; ++jq) {
            float4 a = *(const float4*)(A + jq * 4);
            FMA16(a, W + jq * 128, u);
        }
        if (act) {
            const float4 b = *(const float4*)(wl + LW_BP1 + q * 4);
            float4 o;
            o.x = fmaxf(u.x + b.x, 0.f); o.y = fmaxf(u.y + b.y, 0.f);
            o.z = fmaxf(u.z + b.z, 0.f); o.w = fmaxf(u.w + b.w, 0.f);
            *(float4*)(lds + s * SSTRIDE + OFF_H1 + C1N[w] * 36 + q * 4) = o;
        }
    } else if (w == 7) {
        const float* A = lds + s * SSTRIDE + OFF_AGG + OFF_A10;
        const float* W = tabg + G_W10 + q * 4;
        float4 u = make_float4(0.f,0.f,0.f,0.f);
#pragma unroll 2
        for (int jq = 0; jq < 32; ++jq) {
            float4 a = *(const float4*)(A + jq * 4);
            FMA16(a, W + jq * 128, u);
        }
        if (act) {
            const float4 b = *(const float4*)(wl + LW_BP1 + q * 4);
            float4 o;
            o.x = fmaxf(u.x + b.x, 0.f); o.y = fmaxf(u.y + b.y, 0.f);
            o.z = fmaxf(u.z + b.z, 0.f); o.w = fmaxf(u.w + b.w, 0.f);
            *(float4*)(lds + s * SSTRIDE + OFF_H1 + 10 * 36 + q * 4) = o;
        }
    } else {
        const float* A = lds + s * SSTRIDE + OFF_AGG + OFF_A4;
        const float* W = tabg + G_W4 + q * 4;
        float4 u = make_float4(0.f,0.f,0.f,0.f);
#pragma unroll
        for (int jq = 0; jq < 8; ++jq) {
            float4 a = *(const float4*)(A + jq * 4);
            FMA16(a, W + jq * 128, u);
        }
        if (act) {
            const float4 b = *(const float4*)(wl + LW_B4 + q * 4);   // bias incl sigma0*std-colsum
            float4 o;
            o.x = fmaxf(u.x + b.x, 0.f); o.y = fmaxf(u.y + b.y, 0.f);
            o.z = fmaxf(u.z + b.z, 0.f); o.w = fmaxf(u.w + b.w, 0.f);
            *(float4*)(lds + s * SSTRIDE + OFF_H1 + 4 * 36 + q * 4) = o;
        }
    }
}

// Occupancy law (r2-r11): waves/SIMD = floor(256/VGPR); cap 64 (arg=4) -> 2 blocks/CU.
// EAT precompute removes the 16-reg ea-weight block from fused_conv -> natural demand
// should now fit cap 64 with little/no spill (r11 spilled 132MB; gate: WRITE_SIZE).
extern "C" __global__ void __launch_bounds__(TPB, 4)
pna_main(const float* __restrict__ x_input, const float* __restrict__ edge_attr,
         const float* __restrict__ W_emb,  const float* __restrict__ b_emb,
         const float* __restrict__ W_pre1, const float* __restrict__ b_pre1,
         const float* __restrict__ b_post1,
         const float* __restrict__ W_pre2, const float* __restrict__ b_pre2,
         const float* __restrict__ b_post2,
         const float* __restrict__ wstab,  float* __restrict__ gacc)
{
    extern __shared__ float lds[];
    const int tid = threadIdx.x;
    const int w = __builtin_amdgcn_readfirstlane(tid >> 6);
    const int lane = tid & 63;
    const int s0 = blockIdx.x * SB;
    const int nsamp = min(SB, B_TOT - s0);
    float* wl = lds + WLDS;
    float* pacc = lds + OFF_PACC;

    if (tid < 16) pacc[tid] = 0.f;

    for (int t = tid; t < nsamp * 68; t += TPB)
        lds[(t / 68) * SSTRIDE + OFF_EA + (t % 68)] = edge_attr[(size_t)s0 * 68 + t];

    for (int t = tid; t < nsamp * 352; t += TPB) {
        const int s = t / 352, r = t % 352, n = r >> 5, f = r & 31;
        const float* Xs = x_input + (size_t)(s0 + s) * 44 + n * 4;
        const float* We = W_emb + (n * 4) * 32 + f;
        float v = b_emb[n * 32 + f];
        v = fmaf(Xs[0], We[0],  v);
        v = fmaf(Xs[1], We[32], v);
        v = fmaf(Xs[2], We[64], v);
        v = fmaf(Xs[3], We[96], v);
        lds[s * SSTRIDE + OFF_H + n * 36 + f] = fmaxf(v, 0.f);
    }
    __syncthreads();

    for (int i = 0; i < 3; i++) {
        const float* tab = wstab + i * WTAB;
        // stage small tables -> LDS (356 SM + 32 b_post1)
        if (tid < 89)      ((float4*)wl)[tid] = ((const float4*)(tab + G_SM))[tid];
        else if (tid < 97) ((float4*)(wl + LW_BP1))[tid - 89] = ((const float4*)(b_post1 + i * 32))[tid - 89];

        conv_T<0>(lds, wl, nsamp, w, lane, OFF_H, W_pre1 + i * 2176, b_pre1 + i * 32);
        __syncthreads();                                   // B1: T + EAT1 ready (+ wl staged)
        fused_conv<0>(lds, wl, nsamp, w, lane, 0.f, pacc); // compute, internal barrier, store AGG
        __syncthreads();                                   // B2: AGG ready
        post1_new(lds, wl, nsamp, w, lane, tab);
        __syncthreads();                                   // B3: H1 ready
        conv_T<1>(lds, wl, nsamp, w, lane, OFF_H1, W_pre2 + i * 2176, b_pre2 + i * 32);
        __syncthreads();                                   // B4: T2 + EAT2 ready (incl const TS rows)
        fused_conv<1>(lds, wl, nsamp, w, lane, b_post2[i], pacc);
        __syncthreads();                                   // B5: pacc complete
        if (tid < 11) {
            atomicAdd(gacc + i * 11 + tid, pacc[tid]);
            pacc[tid] = 0.f;
        }
    }
}

extern "C" __global__ void pna_final(const float* __restrict__ ws,
                                     const float* __restrict__ W_fc,
                                     const float* __restrict__ b_fc,
                                     float* __restrict__ out)
{
    const int i = threadIdx.x;
    if (i < 3) {
        float acc = 0.f;
        for (int n = 0; n < 11; n++)
            acc = fmaf(ws[i * 11 + n] * (1.f / 16384.f), W_fc[i * 11 + n], acc);
        const float pc = ws[40 + i];
        const float wsum = W_fc[i * 11 + 0] + W_fc[i * 11 + 1] + W_fc[i * 11 + 2];
        out[i] = acc + pc * wsum + b_fc[i];
    }
}

extern "C" void kernel_launch(void* const* d_in, const int* in_sizes, int n_in,
                              void* d_out, int out_size, void* d_ws, size_t ws_size,
                              hipStream_t stream)
{
    (void)in_sizes; (void)n_in; (void)out_size; (void)ws_size;
    const float* x_input   = (const float*)d_in[0];
    const float* edge_attr = (const float*)d_in[1];
    const float* W_emb     = (const float*)d_in[2];
    const float* b_emb     = (const float*)d_in[3];
    const float* W_pre1    = (const float*)d_in[4];
    const float* b_pre1    = (const float*)d_in[5];
    const float* W_post1   = (const float*)d_in[6];
    const float* b_post1   = (const float*)d_in[7];
    const float* W_pre2    = (const float*)d_in[8];
    const float* b_pre2    = (const float*)d_in[9];
    const float* W_post2   = (const float*)d_in[10];
    const float* b_post2   = (const float*)d_in[11];
    const float* W_fc      = (const float*)d_in[12];
    const float* b_fc      = (const float*)d_in[13];
    float* ws  = (float*)d_ws;
    float* out = (float*)d_out;

    hipLaunchKernelGGL(pna_fold, dim3(64), dim3(512), 0, stream,
                       W_post1, b_post1, W_post2, b_post2, W_pre2, ws);
    const int grid = (B_TOT + SB - 1) / SB;
    const size_t shmem = (size_t)LDS_FLOATS * sizeof(float);
    hipLaunchKernelGGL(pna_main, dim3(grid), dim3(TPB), shmem, stream,
                       x_input, edge_attr, W_emb, b_emb,
                       W_pre1, b_pre1, b_post1,
                       W_pre2, b_pre2, b_post2,
                       ws + WS_TAB, ws);
    hipLaunchKernelGGL(pna_final, dim3(1), dim3(64), 0, stream, ws, W_fc, b_fc, out);
}

// Round 13
// 344.759 us; speedup vs baseline: 1.1910x; 1.1910x over previous
//
#include <hip/hip_runtime.h>
#include <math.h>

#define B_TOT   16384
#define SB      6              // 6 samples/block: conv1-src tasks = 60 <= 64 lanes (binding)
#define TPB     512

// ---- per-sample LDS layout (floats)
#define SSTRIDE 1596
#define OFF_H   0              // 11*36 = 396, lives whole kernel
#define OFF_EA  396            // 68
#define OFF_H1  464            // 396, post1 out -> conv_T2 in
#define OFF_AGG 860            // conv region: TD(288)+TS(396)=684 during conv; AGG(736) after
#define OFF_TD  860            // COMPACT: dst nodes 3..10 at (n-3)*36, 288 floats
#define OFF_TS  1148           // full 11-node src layout, 396 floats
#define OFF_A4  576            // node4 agg offset within AGG (after 6*96 c1 blocks)
#define OFF_A10 608            // node10 agg offset within AGG (608..736)
#define WLDS    (SB * SSTRIDE) // 9576

// ---- LDS weight-table (wl): small tables + WC1 (post1 class1, 6 waves read -> LDS)
#define LW_B4   0              // node4 post1 bias incl sigma0*std-colsum (32)
#define LW_H1C  32             // const h1 row slot (32) [table only]
#define LW_V1C1 64             // class1 post2 vector (96)
#define LW_V10  160            // node10 post2 vector (128)
#define LW_V4   288            // node4 post2 vector (32)
#define LW_C42  320            // node4 post2 sigma0 const (1) + 3 pad
#define LW_TSC  324            // const conv2 src-transform row (nodes 0..2 share) (32)
#define LW_BP1  356            // b_post1 row (32)
#define LW_WC1  388            // class1 post1 [96][32] (3072)
#define LTAB    3460

// ---- EAT: per-sample precomputed ea@Wpre[64:68], 17 edges x 32 f, +4 pad rotates banks
#define EATSTRIDE 548
#define OFF_EAT  (WLDS + LTAB)                 // 13036
#define OFF_PACC (OFF_EAT + SB * EATSTRIDE)    // 16324
#define LDS_FLOATS (OFF_PACC + 16)             // 16340 floats = 65360 B (< 64KB+ limit), 2 blocks/CU
#define AVG_LOG 0.9976091242438673f

// ---- ws per-intervention folded table
#define G_WC1  0               // class1 post1 [96][32]
#define G_W10  3072            // node10 post1 [128][32] (wave 7 only, global/L1)
#define G_W4   7168            // node4 post1 [32][32]  (wave 6 only, global/L1)
#define G_SM   8192            // small tail (356) staged to wl[0..356)
#define WTAB   8548
#define WS_TAB 64              // ws: [0..39] gacc, [40..42] const-node sigmoid

__constant__ int C_ESRC[17] = {0,0,1,1,2,0,3,4,5,6,7,2,8,3,6,9,1};
__constant__ int C1EA[6] = {0,3,5,7,9,11};     // first in-edge of deg-2 nodes
__constant__ int C1EB[6] = {2,4,6,8,10,12};    // second in-edge
__constant__ int C1N[6]  = {3,5,6,7,8,9};      // deg-2 node ids

#define FMA16(a, wb, u) do { \
    float4 w0_ = *(const float4*)(wb); \
    float4 w1_ = *(const float4*)((wb) + 32); \
    float4 w2_ = *(const float4*)((wb) + 64); \
    float4 w3_ = *(const float4*)((wb) + 96); \
    u.x = fmaf(a.x, w0_.x, u.x); u.y = fmaf(a.x, w0_.y, u.y); u.z = fmaf(a.x, w0_.z, u.z); u.w = fmaf(a.x, w0_.w, u.w); \
    u.x = fmaf(a.y, w1_.x, u.x); u.y = fmaf(a.y, w1_.y, u.y); u.z = fmaf(a.y, w1_.z, u.z); u.w = fmaf(a.y, w1_.w, u.w); \
    u.x = fmaf(a.z, w2_.x, u.x); u.y = fmaf(a.z, w2_.y, u.y); u.z = fmaf(a.z, w2_.z, u.z); u.w = fmaf(a.z, w2_.w, u.w); \
    u.x = fmaf(a.w, w3_.x, u.x); u.y = fmaf(a.w, w3_.y, u.y); u.z = fmaf(a.w, w3_.z, u.z); u.w = fmaf(a.w, w3_.w, u.w); \
} while (0)

// message for edge e_: m = relu(base + TS[src] + EAT[e])  -- ea@W precomputed in LDS
#define MSG(e_, m_) do { \
    const float4 ts_ = *(const float4*)(S + OFF_TS + C_ESRC[(e_)] * 36 + f); \
    const float4 ea_ = *(const float4*)(EAT_s + (e_) * 32 + f); \
    m_.x = fmaxf(base.x + ts_.x + ea_.x, 0.f); \
    m_.y = fmaxf(base.y + ts_.y + ea_.y, 0.f); \
    m_.z = fmaxf(base.z + ts_.z + ea_.z, 0.f); \
    m_.w = fmaxf(base.w + ts_.w + ea_.w, 0.f); \
} while (0)

static __device__ __forceinline__ float coef3(const float* __restrict__ W1, int r, int fcol, float amp, float att)
{
    return W1[r * 32 + fcol] + amp * W1[(128 + r) * 32 + fcol] + att * W1[(256 + r) * 32 + fcol];
}
static __device__ __forceinline__ float coef3s(const float* __restrict__ W2, int r, float amp, float att)
{
    return W2[r] + amp * W2[128 + r] + att * W2[256 + r];
}

// ---- one-shot fold: amp/att per degree class + graph-structure identities
extern "C" __global__ void pna_fold(const float* __restrict__ W_post1, const float* __restrict__ b_post1,
                                    const float* __restrict__ W_post2, const float* __restrict__ b_post2,
                                    const float* __restrict__ W_pre2,  float* __restrict__ ws)
{
    const int t0 = blockIdx.x * blockDim.x + threadIdx.x;
    const int NT = gridDim.x * blockDim.x;
    const float l1 = log1pf(1.f), l2 = log1pf(2.f), l4 = log1pf(4.f);
    const float amp1 = l1 / AVG_LOG, att1 = AVG_LOG / l1;
    const float amp2 = l2 / AVG_LOG, att2 = AVG_LOG / l2;
    const float amp4 = l4 / AVG_LOG, att4 = AVG_LOG / l4;
    const float SIG0 = 0.0031622776601683794f;   // sqrt(1e-5)

    for (int idx = t0; idx < 3 * WTAB; idx += NT) {
        const int i = idx / WTAB, off = idx % WTAB;
        const float* W1 = W_post1 + i * 384 * 32;
        const float* W2 = W_post2 + i * 384;
        float val = 0.f;
        if (off < 3072) {                                   // WC1: deg-2 fold (mx = 2*mean - mn)
            const int j = off >> 5, fcol = off & 31, sub = j >> 5, jj = j & 31;
            if (sub == 0)      val = coef3(W1, jj, fcol, amp2, att2) + 2.f * coef3(W1, 64 + jj, fcol, amp2, att2);
            else if (sub == 1) val = coef3(W1, 32 + jj, fcol, amp2, att2) - coef3(W1, 64 + jj, fcol, amp2, att2);
            else               val = coef3(W1, 96 + jj, fcol, amp2, att2);
        } else if (off < 7168) {                            // W10: full [mean|mn|mx|std] rows
            const int rr = off - 3072;
            val = coef3(W1, rr >> 5, rr & 31, amp4, att4);
        } else if (off < 8192) {                            // W4: Wm+Wmn+Wmx fold
            const int rr = off - 7168, jj = rr >> 5, fcol = rr & 31;
            val = coef3(W1, jj, fcol, amp1, att1) + coef3(W1, 32 + jj, fcol, amp1, att1)
                + coef3(W1, 64 + jj, fcol, amp1, att1);
        } else if (off < 8224) {                            // B4
            const int fcol = off - 8192;
            float ssum = 0.f;
            for (int jj = 0; jj < 32; ++jj) ssum += coef3(W1, 96 + jj, fcol, amp1, att1);
            val = b_post1[i * 32 + fcol] + SIG0 * ssum;
        } else if (off < 8256) {                            // H1C (const rows, nodes 0..2)
            const int fcol = off - 8224;
            float ssum = 0.f;
            for (int jj = 0; jj < 32; ++jj) ssum += coef3(W1, 96 + jj, fcol, amp1, att1);
            val = fmaxf(b_post1[i * 32 + fcol] + SIG0 * ssum, 0.f);
        } else if (off < 8352) {                            // V1C1
            const int j = off - 8256, sub = j >> 5, jj = j & 31;
            if (sub == 0)      val = coef3s(W2, jj, amp2, att2) + 2.f * coef3s(W2, 64 + jj, amp2, att2);
            else if (sub == 1) val = coef3s(W2, 32 + jj, amp2, att2) - coef3s(W2, 64 + jj, amp2, att2);
            else               val = coef3s(W2, 96 + jj, amp2, att2);
        } else if (off < 8480) {                            // V10
            val = coef3s(W2, off - 8352, amp4, att4);
        } else if (off < 8512) {                            // V4
            const int jj = off - 8480;
            val = coef3s(W2, jj, amp1, att1) + coef3s(W2, 32 + jj, amp1, att1) + coef3s(W2, 64 + jj, amp1, att1);
        } else if (off == 8512) {                           // C42
            float ssum = 0.f;
            for (int jj = 0; jj < 32; ++jj) ssum += coef3s(W2, 96 + jj, amp1, att1);
            val = SIG0 * ssum;
        } else if (off >= 8516 && off < 8548) {             // TSC: conv2 src-transform of const h1 (nodes 0..2)
            const int fcol = off - 8516;
            const float* Wp2 = W_pre2 + i * 2176;
            float acc = 0.f;
            for (int k = 0; k < 32; ++k) {
                float ssum = 0.f;
                for (int jj = 0; jj < 32; ++jj) ssum += coef3(W1, 96 + jj, k, amp1, att1);
                const float h1c = fmaxf(b_post1[i * 32 + k] + SIG0 * ssum, 0.f);
                acc = fmaf(h1c, Wp2[(32 + k) * 32 + fcol], acc);
            }
            val = acc;
        }
        ws[WS_TAB + idx] = val;
    }
    if (t0 < 40) ws[t0] = 0.f;                              // gacc zero
    if (t0 >= 40 && t0 < 43) {                              // const-node sigmoid per intervention
        const int i = t0 - 40;
        const float* W2 = W_post2 + i * 384;
        float ssum = 0.f;
        for (int jj = 0; jj < 32; ++jj) ssum += coef3s(W2, 96 + jj, amp1, att1);
        ws[40 + i] = 1.f / (1.f + expf(-(b_post2[i] + SIG0 * ssum)));
    }
}

// ---- per-node transform + EAT precompute. dst waves (ty=0): nodes 3..10 -> compact TD.
// src waves (ty=1): conv1 nodes 0..9 (10); conv2 nodes 3..9 (7) + const TS copy for 0..2.
// Appendix (all threads): EAT[s][e][f] = ea[s][e] @ Wp[64:68] (weights from global, L1-hot).
template<int PASS>
static __device__ __forceinline__ void conv_T(float* lds, const float* wl, int nsamp, int w, int lane,
                                              int hoff, const float* __restrict__ Wp,
                                              const float* __restrict__ bp)
{
    const int ty = w & 1;
    const int f0 = (w >> 1) * 8;
    int s, n, tasks;
    if (ty == 0)            { tasks = nsamp * 8;  s = lane >> 3;  n = 3 + (lane & 7); }
    else if (PASS == 0)     { tasks = nsamp * 10; s = lane / 10;  n = lane % 10; }
    else                    { tasks = nsamp * 7;  s = lane / 7;   n = 3 + lane % 7; }
    const bool act = lane < tasks;
    if (!act) { s = 0; n = 3; }
    const float* Hrow = lds + s * SSTRIDE + hoff + n * 36;
    const float* wbase = Wp + ty * 32 * 32 + f0;        // wave-uniform -> s_load
    float acc[8];
#pragma unroll
    for (int f = 0; f < 8; f++) acc[f] = ty ? 0.f : bp[f0 + f];
#pragma unroll
    for (int kq = 0; kq < 8; kq++) {
        float4 a = *(const float4*)(Hrow + kq * 4);
#pragma unroll
        for (int kk = 0; kk < 4; kk++) {
            float av = (kk == 0) ? a.x : (kk == 1) ? a.y : (kk == 2) ? a.z : a.w;
            const float* wr = wbase + (kq * 4 + kk) * 32;
#pragma unroll
            for (int f = 0; f < 8; f++) acc[f] = fmaf(av, wr[f], acc[f]);
        }
    }
    float* T = lds + s * SSTRIDE + (ty ? (OFF_TS + n * 36) : (OFF_TD + (n - 3) * 36)) + f0;
    if (act) {
        *(float4*)(T + 0) = make_float4(acc[0], acc[1], acc[2], acc[3]);
        *(float4*)(T + 4) = make_float4(acc[4], acc[5], acc[6], acc[7]);
    }
    if (PASS == 1 && ty == 1) {                         // const TS rows (nodes 0..2 share one vector)
        if (lane < nsamp * 3) {
            const int cs = lane / 3, cn = lane % 3;
            float* Tc = lds + cs * SSTRIDE + OFF_TS + cn * 36 + f0;
            *(float4*)(Tc)     = *(const float4*)(wl + LW_TSC + f0);
            *(float4*)(Tc + 4) = *(const float4*)(wl + LW_TSC + f0 + 4);
        }
    }
    // EAT appendix: tasks = nsamp*17*8 (e, f-quad); weights from global rows 64..67 (L1-hot)
    const int tid2 = (w << 6) | lane;
    for (int t = tid2; t < nsamp * 136; t += TPB) {
        const int s2 = t / 136, r2 = t - s2 * 136, e2 = r2 >> 3, fo = (r2 & 7) * 4;
        const float4 ev = *(const float4*)(lds + s2 * SSTRIDE + OFF_EA + e2 * 4);
        const float4 wa = *(const float4*)(Wp + 2048 + fo);
        const float4 wb = *(const float4*)(Wp + 2080 + fo);
        const float4 wc = *(const float4*)(Wp + 2112 + fo);
        const float4 wd = *(const float4*)(Wp + 2144 + fo);
        float4 t4;
        t4.x = ev.x * wa.x; t4.y = ev.x * wa.y; t4.z = ev.x * wa.z; t4.w = ev.x * wa.w;
        t4.x = fmaf(ev.y, wb.x, t4.x); t4.y = fmaf(ev.y, wb.y, t4.y);
        t4.z = fmaf(ev.y, wb.z, t4.z); t4.w = fmaf(ev.y, wb.w, t4.w);
        t4.x = fmaf(ev.z, wc.x, t4.x); t4.y = fmaf(ev.z, wc.y, t4.y);
        t4.z = fmaf(ev.z, wc.z, t4.z); t4.w = fmaf(ev.z, wc.w, t4.w);
        t4.x = fmaf(ev.w, wd.x, t4.x); t4.y = fmaf(ev.w, wd.y, t4.y);
        t4.z = fmaf(ev.w, wd.z, t4.z); t4.w = fmaf(ev.w, wd.w, t4.w);
        *(float4*)(lds + OFF_EAT + s2 * EATSTRIDE + e2 * 32 + fo) = t4;
    }
}

// ---- fused message+aggregate, EAT-based (no weight regs). wave = node class.
// CONV2=0: compute agg in regs, barrier, store AGG. CONV2=1: dot with folded post2
// vector, shfl-reduce, sigmoid, LDS-atomic pacc.
template<int CONV2>
static __device__ __forceinline__ void fused_conv(float* lds, const float* wl, int nsamp,
                                                  int w, int lane, float b2, float* pacc)
{
    const bool act = lane < nsamp * 8;
    const int l = act ? lane : 0;
    const int s = l >> 3, q = l & 7, f = q * 4;
    float* S = lds + s * SSTRIDE;
    const float* EAT_s = lds + OFF_EAT + s * EATSTRIDE;

    float4 r0 = make_float4(0.f,0.f,0.f,0.f), r1 = r0, r2 = r0, r3 = r0;
    float u = 0.f;

    if (w < 6) {                                           // deg-2 node C1N[w]
        float4 base = *(const float4*)(S + OFF_TD + (C1N[w] - 3) * 36 + f);
        float4 ma, mb;
        MSG(C1EA[w], ma);
        MSG(C1EB[w], mb);
        r0.x = (ma.x + mb.x) * 0.5f; r0.y = (ma.y + mb.y) * 0.5f;
        r0.z = (ma.z + mb.z) * 0.5f; r0.w = (ma.w + mb.w) * 0.5f;
        r1.x = fminf(ma.x, mb.x); r1.y = fminf(ma.y, mb.y);
        r1.z = fminf(ma.z, mb.z); r1.w = fminf(ma.w, mb.w);
        float4 msq;
        msq.x = fmaf(mb.x, mb.x, ma.x * ma.x) * 0.5f;
        msq.y = fmaf(mb.y, mb.y, ma.y * ma.y) * 0.5f;
        msq.z = fmaf(mb.z, mb.z, ma.z * ma.z) * 0.5f;
        msq.w = fmaf(mb.w, mb.w, ma.w * ma.w) * 0.5f;
        r2.x = sqrtf(fmaxf(msq.x - r0.x * r0.x, 0.f) + 1e-5f);
        r2.y = sqrtf(fmaxf(msq.y - r0.y * r0.y, 0.f) + 1e-5f);
        r2.z = sqrtf(fmaxf(msq.z - r0.z * r0.z, 0.f) + 1e-5f);
        r2.w = sqrtf(fmaxf(msq.w - r0.w * r0.w, 0.f) + 1e-5f);
        if (CONV2) {
            const float* V = wl + LW_V1C1 + f;
            const float4 v0 = *(const float4*)(V);
            const float4 v1 = *(const float4*)(V + 32);
            const float4 v2 = *(const float4*)(V + 64);
            u = fmaf(r0.x, v0.x, fmaf(r0.y, v0.y, fmaf(r0.z, v0.z, r0.w * v0.w)));
            u = fmaf(r1.x, v1.x, fmaf(r1.y, v1.y, fmaf(r1.z, v1.z, fmaf(r1.w, v1.w, u))));
            u = fmaf(r2.x, v2.x, fmaf(r2.y, v2.y, fmaf(r2.z, v2.z, fmaf(r2.w, v2.w, u))));
        }
    } else if (w == 6) {                                   // node4 (deg-1): agg = message
        float4 base = *(const float4*)(S + OFF_TD + 1 * 36 + f);   // node4 -> compact idx 1
        float4 m;
        MSG(1, m);
        r0 = m;
        if (CONV2) {
            const float4 v0 = *(const float4*)(wl + LW_V4 + f);
            u = fmaf(m.x, v0.x, fmaf(m.y, v0.y, fmaf(m.z, v0.z, m.w * v0.w)));
        }
    } else {                                               // node10 (deg-4), edges 13..16
        float4 base = *(const float4*)(S + OFF_TD + 7 * 36 + f);   // node10 -> compact idx 7
        float4 sum = make_float4(0.f,0.f,0.f,0.f), sq = sum;
        float4 mn = make_float4(1e30f,1e30f,1e30f,1e30f);
        float4 mx = make_float4(-1e30f,-1e30f,-1e30f,-1e30f);
#pragma unroll
        for (int e = 13; e <= 16; ++e) {
            float4 m;
            MSG(e, m);
            sum.x += m.x; sum.y += m.y; sum.z += m.z; sum.w += m.w;
            sq.x = fmaf(m.x, m.x, sq.x); sq.y = fmaf(m.y, m.y, sq.y);
            sq.z = fmaf(m.z, m.z, sq.z); sq.w = fmaf(m.w, m.w, sq.w);
            mn.x = fminf(mn.x, m.x); mn.y = fminf(mn.y, m.y); mn.z = fminf(mn.z, m.z); mn.w = fminf(mn.w, m.w);
            mx.x = fmaxf(mx.x, m.x); mx.y = fmaxf(mx.y, m.y); mx.z = fmaxf(mx.z, m.z); mx.w = fmaxf(mx.w, m.w);
        }
        r0.x = sum.x * 0.25f; r0.y = sum.y * 0.25f; r0.z = sum.z * 0.25f; r0.w = sum.w * 0.25f;
        r1 = mn; r2 = mx;
        float4 msq = make_float4(sq.x * 0.25f, sq.y * 0.25f, sq.z * 0.25f, sq.w * 0.25f);
        r3.x = sqrtf(fmaxf(msq.x - r0.x * r0.x, 0.f) + 1e-5f);
        r3.y = sqrtf(fmaxf(msq.y - r0.y * r0.y, 0.f) + 1e-5f);
        r3.z = sqrtf(fmaxf(msq.z - r0.z * r0.z, 0.f) + 1e-5f);
        r3.w = sqrtf(fmaxf(msq.w - r0.w * r0.w, 0.f) + 1e-5f);
        if (CONV2) {
            const float* V = wl + LW_V10 + f;
            const float4 v0 = *(const float4*)(V);
            const float4 v1 = *(const float4*)(V + 32);
            const float4 v2 = *(const float4*)(V + 64);
            const float4 v3 = *(const float4*)(V + 96);
            u = fmaf(r0.x, v0.x, fmaf(r0.y, v0.y, fmaf(r0.z, v0.z, r0.w * v0.w)));
            u = fmaf(r1.x, v1.x, fmaf(r1.y, v1.y, fmaf(r1.z, v1.z, fmaf(r1.w, v1.w, u))));
            u = fmaf(r2.x, v2.x, fmaf(r2.y, v2.y, fmaf(r2.z, v2.z, fmaf(r2.w, v2.w, u))));
            u = fmaf(r3.x, v3.x, fmaf(r3.y, v3.y, fmaf(r3.z, v3.z, fmaf(r3.w, v3.w, u))));
        }
    }

    if (!CONV2) {
        __syncthreads();                                   // all reads of TD/TS/EAT done before AGG overwrite
        if (act) {
            if (w < 6) {
                float* A = S + OFF_AGG + w * 96;
                *(float4*)(A + f) = r0; *(float4*)(A + 32 + f) = r1; *(float4*)(A + 64 + f) = r2;
            } else if (w == 6) {
                *(float4*)(S + OFF_AGG + OFF_A4 + f) = r0;
            } else {
                float* A = S + OFF_AGG + OFF_A10;
                *(float4*)(A + f) = r0; *(float4*)(A + 32 + f) = r1;
                *(float4*)(A + 64 + f) = r2; *(float4*)(A + 96 + f) = r3;
            }
        }
    } else {
        u += __shfl_xor(u, 1);
        u += __shfl_xor(u, 2);
        u += __shfl_xor(u, 4);
        if (act && q == 0) {
            const float extra = (w == 6) ? wl[LW_C42] : 0.f;
            const int node = (w < 6) ? C1N[w] : (w == 6 ? 4 : 10);
            const float p = 1.f / (1.f + expf(-(u + b2 + extra)));
            atomicAdd(pacc + node, p);
        }
    }
}

// ---- post1: waves 0..5 class1 (weights LDS-broadcast from wl), wave 6 node4 (global),
//      wave 7 node10 (global, 1 wave -> L1-resident).
static __device__ __forceinline__ void post1_new(float* lds, const float* wl, int nsamp, int w, int lane,
                                                 const float* __restrict__ tabg)
{
    const bool act = lane < nsamp * 8;
    const int l = act ? lane : 0;
    const int s = l >> 3, q = l & 7;
    if (w < 6) {
        const float* A = lds + s * SSTRIDE + OFF_AGG + w * 96;
        const float* W = wl + LW_WC1 + q * 4;
        float4 u = make_float4(0.f,0.f,0.f,0.f);
#pragma unroll 2
        for (int jq = 0; jq < 24; ++jq) {
            float4 a = *(const float4*)(A + jq * 4);
            FMA16(a, W + jq * 128, u);
        }
        if (act) {
            const float4 b = *(const float4*)(wl + LW_BP1 + q * 4);
            float4 o;
            o.x = fmaxf(u.x + b.x, 0.f); o.y = fmaxf(u.y + b.y, 0.f);
            o.z = fmaxf(u.z + b.z, 0.f); o.w = fmaxf(u.w + b.w, 0.f);
            *(float4*)(lds + s * SSTRIDE + OFF_H1 + C1N[w] * 36 + q * 4) = o;
        }
    } else if (w == 7) {
        const float* A = lds + s * SSTRIDE + OFF_AGG + OFF_A10;
        const float* W = tabg + G_W10 + q * 4;
        float4 u = make_float4(0.f,0.f,0.f,0.f);
#pragma unroll 2
        for (int jq = 0; jq < 32; ++jq) {
            float4 a = *(const float4*)(A + jq * 4);
            FMA16(a, W + jq * 128, u);
        }
        if (act) {
            const float4 b = *(const float4*)(wl + LW_BP1 + q * 4);
            float4 o;
            o.x = fmaxf(u.x + b.x, 0.f); o.y = fmaxf(u.y + b.y, 0.f);
            o.z = fmaxf(u.z + b.z, 0.f); o.w = fmaxf(u.w + b.w, 0.f);
            *(float4*)(lds + s * SSTRIDE + OFF_H1 + 10 * 36 + q * 4) = o;
        }
    } else {
        const float* A = lds + s * SSTRIDE + OFF_AGG + OFF_A4;
        const float* W = tabg + G_W4 + q * 4;
        float4 u = make_float4(0.f,0.f,0.f,0.f);
#pragma unroll
        for (int jq = 0; jq < 8; ++jq) {
            float4 a = *(const float4*)(A + jq * 4);
            FMA16(a, W + jq * 128, u);
        }
        if (act) {
            const float4 b = *(const float4*)(wl + LW_B4 + q * 4);   // bias incl sigma0*std-colsum
            float4 o;
            o.x = fmaxf(u.x + b.x, 0.f); o.y = fmaxf(u.y + b.y, 0.f);
            o.z = fmaxf(u.z + b.z, 0.f); o.w = fmaxf(u.w + b.w, 0.f);
            *(float4*)(lds + s * SSTRIDE + OFF_H1 + 4 * 36 + q * 4) = o;
        }
    }
}

// Occupancy law (r2-r12): waves/SIMD = floor(256/VGPR); cap 64 (arg=4) -> 2 blocks/CU.
// r12 proved EAT removes the spill (WRITE 132->5MB) but WC1-from-global made post1
// latency-bound (+79us). This round: EAT kept, WC1 back in LDS via TD/AGG compaction.
extern "C" __global__ void __launch_bounds__(TPB, 4)
pna_main(const float* __restrict__ x_input, const float* __restrict__ edge_attr,
         const float* __restrict__ W_emb,  const float* __restrict__ b_emb,
         const float* __restrict__ W_pre1, const float* __restrict__ b_pre1,
         const float* __restrict__ b_post1,
         const float* __restrict__ W_pre2, const float* __restrict__ b_pre2,
         const float* __restrict__ b_post2,
         const float* __restrict__ wstab,  float* __restrict__ gacc)
{
    extern __shared__ float lds[];
    const int tid = threadIdx.x;
    const int w = __builtin_amdgcn_readfirstlane(tid >> 6);
    const int lane = tid & 63;
    const int s0 = blockIdx.x * SB;
    const int nsamp = min(SB, B_TOT - s0);
    float* wl = lds + WLDS;
    float* pacc = lds + OFF_PACC;

    if (tid < 16) pacc[tid] = 0.f;

    for (int t = tid; t < nsamp * 68; t += TPB)
        lds[(t / 68) * SSTRIDE + OFF_EA + (t % 68)] = edge_attr[(size_t)s0 * 68 + t];

    for (int t = tid; t < nsamp * 352; t += TPB) {
        const int s = t / 352, r = t % 352, n = r >> 5, f = r & 31;
        const float* Xs = x_input + (size_t)(s0 + s) * 44 + n * 4;
        const float* We = W_emb + (n * 4) * 32 + f;
        float v = b_emb[n * 32 + f];
        v = fmaf(Xs[0], We[0],  v);
        v = fmaf(Xs[1], We[32], v);
        v = fmaf(Xs[2], We[64], v);
        v = fmaf(Xs[3], We[96], v);
        lds[s * SSTRIDE + OFF_H + n * 36 + f] = fmaxf(v, 0.f);
    }
    __syncthreads();

    for (int i = 0; i < 3; i++) {
        const float* tab = wstab + i * WTAB;
        // stage WC1 (768 float4) + small tables -> LDS
        for (int t = tid; t < 768; t += TPB)
            ((float4*)(wl + LW_WC1))[t] = ((const float4*)(tab + G_WC1))[t];
        if (tid < 89)      ((float4*)wl)[tid] = ((const float4*)(tab + G_SM))[tid];
        else if (tid < 97) ((float4*)(wl + LW_BP1))[tid - 89] = ((const float4*)(b_post1 + i * 32))[tid - 89];

        conv_T<0>(lds, wl, nsamp, w, lane, OFF_H, W_pre1 + i * 2176, b_pre1 + i * 32);
        __syncthreads();                                   // B1: T + EAT1 ready (+ wl staged)
        fused_conv<0>(lds, wl, nsamp, w, lane, 0.f, pacc); // compute, internal barrier, store AGG
        __syncthreads();                                   // B2: AGG ready
        post1_new(lds, wl, nsamp, w, lane, tab);
        __syncthreads();                                   // B3: H1 ready
        conv_T<1>(lds, wl, nsamp, w, lane, OFF_H1, W_pre2 + i * 2176, b_pre2 + i * 32);
        __syncthreads();                                   // B4: T2 + EAT2 ready (incl const TS rows)
        fused_conv<1>(lds, wl, nsamp, w, lane, b_post2[i], pacc);
        __syncthreads();                                   // B5: pacc complete
        if (tid < 11) {
            atomicAdd(gacc + i * 11 + tid, pacc[tid]);
            pacc[tid] = 0.f;
        }
    }
}

extern "C" __global__ void pna_final(const float* __restrict__ ws,
                                     const float* __restrict__ W_fc,
                                     const float* __restrict__ b_fc,
                                     float* __restrict__ out)
{
    const int i = threadIdx.x;
    if (i < 3) {
        float acc = 0.f;
        for (int n = 0; n < 11; n++)
            acc = fmaf(ws[i * 11 + n] * (1.f / 16384.f), W_fc[i * 11 + n], acc);
        const float pc = ws[40 + i];
        const float wsum = W_fc[i * 11 + 0] + W_fc[i * 11 + 1] + W_fc[i * 11 + 2];
        out[i] = acc + pc * wsum + b_fc[i];
    }
}

extern "C" void kernel_launch(void* const* d_in, const int* in_sizes, int n_in,
                              void* d_out, int out_size, void* d_ws, size_t ws_size,
                              hipStream_t stream)
{
    (void)in_sizes; (void)n_in; (void)out_size; (void)ws_size;
    const float* x_input   = (const float*)d_in[0];
    const float* edge_attr = (const float*)d_in[1];
    const float* W_emb     = (const float*)d_in[2];
    const float* b_emb     = (const float*)d_in[3];
    const float* W_pre1    = (const float*)d_in[4];
    const float* b_pre1    = (const float*)d_in[5];
    const float* W_post1   = (const float*)d_in[6];
    const float* b_post1   = (const float*)d_in[7];
    const float* W_pre2    = (const float*)d_in[8];
    const float* b_pre2    = (const float*)d_in[9];
    const float* W_post2   = (const float*)d_in[10];
    const float* b_post2   = (const float*)d_in[11];
    const float* W_fc      = (const float*)d_in[12];
    const float* b_fc      = (const float*)d_in[13];
    float* ws  = (float*)d_ws;
    float* out = (float*)d_out;

    hipLaunchKernelGGL(pna_fold, dim3(64), dim3(512), 0, stream,
                       W_post1, b_post1, W_post2, b_post2, W_pre2, ws);
    const int grid = (B_TOT + SB - 1) / SB;
    const size_t shmem = (size_t)LDS_FLOATS * sizeof(float);
    hipLaunchKernelGGL(pna_main, dim3(grid), dim3(TPB), shmem, stream,
                       x_input, edge_attr, W_emb, b_emb,
                       W_pre1, b_pre1, b_post1,
                       W_pre2, b_pre2, b_post2,
                       ws + WS_TAB, ws);
    hipLaunchKernelGGL(pna_final, dim3(1), dim3(64), 0, stream, ws, W_fc, b_fc, out);
}

// Round 15
// 324.980 us; speedup vs baseline: 1.2635x; 1.0609x over previous
//
#include <hip/hip_runtime.h>
#include <math.h>

#define B_TOT   16384
#define SB      6              // 6 samples/block: conv1-src tasks = 60 <= 64 lanes (binding)
#define TPB     512

// ---- per-sample LDS layout (floats)
#define SSTRIDE 1652
#define OFF_H   0              // 11*36 = 396, lives whole kernel
#define OFF_EA  396            // 68
#define OFF_H1  464            // 396, post1 out -> conv_T2 in
#define OFF_AGG 860            // 792-region: TD/TS during conv; AGG after fused store
#define OFF_TD  OFF_AGG
#define OFF_TS  (OFF_AGG + 396)
#define OFF_A4  600            // node4 agg offset within AGG region
#define OFF_A10 640            // node10 agg offset within AGG region
#define WLDS    (SB * SSTRIDE) // 9912

// ---- LDS weight-table (wl) layout (mirrors ws SM block order)
#define LW_B4   0              // node4 post1 bias incl sigma0*std-colsum (32)
#define LW_H1C  32             // const h1 row for nodes 0..2 (32) [table only]
#define LW_V1C1 64             // class1 post2 vector (96)
#define LW_V10  160            // node10 post2 vector (128)
#define LW_V4   288            // node4 post2 vector (32)
#define LW_C42  320            // node4 post2 sigma0 const (1) + 3 pad
#define LW_TSC  324            // const conv2 src-transform row (nodes 0..2 share it) (32)
#define LW_BP1  356            // b_post1 row (32)
#define LW_EA1  388            // W_pre1 rows 64..67 (128)
#define LW_EA2  516            // W_pre2 rows 64..67 (128)
#define LW_WC1  644            // class1 post1 [96][32] (read by 6 waves) (3072)
#define LTAB    3716

#define OFF_PACC (WLDS + LTAB)
#define LDS_FLOATS (WLDS + LTAB + 16)   // 13644 floats = 54576 B -> 2 blocks/CU (VGPR-capped anyway)
#define AVG_LOG 0.9976091242438673f

// ---- ws per-intervention folded table
#define G_WC1  0               // class1 post1 [96][32]
#define G_W10  3072            // node10 post1 [128][32] (wave 7 only, global/L1)
#define G_W4   7168            // node4 post1 [32][32]  (wave 6 only, global/L1)
#define G_SM   8192            // small tail (356) staged to wl[0..356)
#define WTAB   8548
#define WS_TAB 64              // ws: [0..39] gacc, [40..42] const-node sigmoid

__constant__ int C_ESRC[17] = {0,0,1,1,2,0,3,4,5,6,7,2,8,3,6,9,1};
__constant__ int C1EA[6] = {0,3,5,7,9,11};     // first in-edge of deg-2 nodes
__constant__ int C1EB[6] = {2,4,6,8,10,12};    // second in-edge
__constant__ int C1N[6]  = {3,5,6,7,8,9};      // deg-2 node ids

#define FMA16(a, wb, u) do { \
    float4 w0_ = *(const float4*)(wb); \
    float4 w1_ = *(const float4*)((wb) + 32); \
    float4 w2_ = *(const float4*)((wb) + 64); \
    float4 w3_ = *(const float4*)((wb) + 96); \
    u.x = fmaf(a.x, w0_.x, u.x); u.y = fmaf(a.x, w0_.y, u.y); u.z = fmaf(a.x, w0_.z, u.z); u.w = fmaf(a.x, w0_.w, u.w); \
    u.x = fmaf(a.y, w1_.x, u.x); u.y = fmaf(a.y, w1_.y, u.y); u.z = fmaf(a.y, w1_.z, u.z); u.w = fmaf(a.y, w1_.w, u.w); \
    u.x = fmaf(a.z, w2_.x, u.x); u.y = fmaf(a.z, w2_.y, u.y); u.z = fmaf(a.z, w2_.z, u.z); u.w = fmaf(a.z, w2_.w, u.w); \
    u.x = fmaf(a.w, w3_.x, u.x); u.y = fmaf(a.w, w3_.y, u.y); u.z = fmaf(a.w, w3_.z, u.z); u.w = fmaf(a.w, w3_.w, u.w); \
} while (0)

// message for edge e_: m = relu(TDquad(base) + TSquad(src) + ea@Wrows64..67)  [r7 form]
#define MSG(e_, m_) do { \
    const float4 ev_ = *(const float4*)(S + OFF_EA + (e_) * 4); \
    const float4 ts_ = *(const float4*)(S + OFF_TS + C_ESRC[(e_)] * 36 + f); \
    m_.x = base.x + ts_.x; m_.y = base.y + ts_.y; m_.z = base.z + ts_.z; m_.w = base.w + ts_.w; \
    m_.x = fmaf(ev_.x, w0.x, m_.x); m_.y = fmaf(ev_.x, w0.y, m_.y); m_.z = fmaf(ev_.x, w0.z, m_.z); m_.w = fmaf(ev_.x, w0.w, m_.w); \
    m_.x = fmaf(ev_.y, w1.x, m_.x); m_.y = fmaf(ev_.y, w1.y, m_.y); m_.z = fmaf(ev_.y, w1.z, m_.z); m_.w = fmaf(ev_.y, w1.w, m_.w); \
    m_.x = fmaf(ev_.z, w2.x, m_.x); m_.y = fmaf(ev_.z, w2.y, m_.y); m_.z = fmaf(ev_.z, w2.z, m_.z); m_.w = fmaf(ev_.z, w2.w, m_.w); \
    m_.x = fmaf(ev_.w, w3.x, m_.x); m_.y = fmaf(ev_.w, w3.y, m_.y); m_.z = fmaf(ev_.w, w3.z, m_.z); m_.w = fmaf(ev_.w, w3.w, m_.w); \
    m_.x = fmaxf(m_.x, 0.f); m_.y = fmaxf(m_.y, 0.f); m_.z = fmaxf(m_.z, 0.f); m_.w = fmaxf(m_.w, 0.f); \
} while (0)

static __device__ __forceinline__ float coef3(const float* __restrict__ W1, int r, int fcol, float amp, float att)
{
    return W1[r * 32 + fcol] + amp * W1[(128 + r) * 32 + fcol] + att * W1[(256 + r) * 32 + fcol];
}
static __device__ __forceinline__ float coef3s(const float* __restrict__ W2, int r, float amp, float att)
{
    return W2[r] + amp * W2[128 + r] + att * W2[256 + r];
}

// ---- one-shot fold: amp/att per degree class + graph-structure identities
extern "C" __global__ void pna_fold(const float* __restrict__ W_post1, const float* __restrict__ b_post1,
                                    const float* __restrict__ W_post2, const float* __restrict__ b_post2,
                                    const float* __restrict__ W_pre2,  float* __restrict__ ws)
{
    const int t0 = blockIdx.x * blockDim.x + threadIdx.x;
    const int NT = gridDim.x * blockDim.x;
    const float l1 = log1pf(1.f), l2 = log1pf(2.f), l4 = log1pf(4.f);
    const float amp1 = l1 / AVG_LOG, att1 = AVG_LOG / l1;
    const float amp2 = l2 / AVG_LOG, att2 = AVG_LOG / l2;
    const float amp4 = l4 / AVG_LOG, att4 = AVG_LOG / l4;
    const float SIG0 = 0.0031622776601683794f;   // sqrt(1e-5)

    for (int idx = t0; idx < 3 * WTAB; idx += NT) {
        const int i = idx / WTAB, off = idx % WTAB;
        const float* W1 = W_post1 + i * 384 * 32;
        const float* W2 = W_post2 + i * 384;
        float val = 0.f;
        if (off < 3072) {                                   // WC1: deg-2 fold (mx = 2*mean - mn)
            const int j = off >> 5, fcol = off & 31, sub = j >> 5, jj = j & 31;
            if (sub == 0)      val = coef3(W1, jj, fcol, amp2, att2) + 2.f * coef3(W1, 64 + jj, fcol, amp2, att2);
            else if (sub == 1) val = coef3(W1, 32 + jj, fcol, amp2, att2) - coef3(W1, 64 + jj, fcol, amp2, att2);
            else               val = coef3(W1, 96 + jj, fcol, amp2, att2);
        } else if (off < 7168) {                            // W10: full [mean|mn|mx|std] rows
            const int rr = off - 3072;
            val = coef3(W1, rr >> 5, rr & 31, amp4, att4);
        } else if (off < 8192) {                            // W4: Wm+Wmn+Wmx fold
            const int rr = off - 7168, jj = rr >> 5, fcol = rr & 31;
            val = coef3(W1, jj, fcol, amp1, att1) + coef3(W1, 32 + jj, fcol, amp1, att1)
                + coef3(W1, 64 + jj, fcol, amp1, att1);
        } else if (off < 8224) {                            // B4
            const int fcol = off - 8192;
            float ssum = 0.f;
            for (int jj = 0; jj < 32; ++jj) ssum += coef3(W1, 96 + jj, fcol, amp1, att1);
            val = b_post1[i * 32 + fcol] + SIG0 * ssum;
        } else if (off < 8256) {                            // H1C (const rows, nodes 0..2)
            const int fcol = off - 8224;
            float ssum = 0.f;
            for (int jj = 0; jj < 32; ++jj) ssum += coef3(W1, 96 + jj, fcol, amp1, att1);
            val = fmaxf(b_post1[i * 32 + fcol] + SIG0 * ssum, 0.f);
        } else if (off < 8352) {                            // V1C1
            const int j = off - 8256, sub = j >> 5, jj = j & 31;
            if (sub == 0)      val = coef3s(W2, jj, amp2, att2) + 2.f * coef3s(W2, 64 + jj, amp2, att2);
            else if (sub == 1) val = coef3s(W2, 32 + jj, amp2, att2) - coef3s(W2, 64 + jj, amp2, att2);
            else               val = coef3s(W2, 96 + jj, amp2, att2);
        } else if (off < 8480) {                            // V10
            val = coef3s(W2, off - 8352, amp4, att4);
        } else if (off < 8512) {                            // V4
            const int jj = off - 8480;
            val = coef3s(W2, jj, amp1, att1) + coef3s(W2, 32 + jj, amp1, att1) + coef3s(W2, 64 + jj, amp1, att1);
        } else if (off == 8512) {                           // C42
            float ssum = 0.f;
            for (int jj = 0; jj < 32; ++jj) ssum += coef3s(W2, 96 + jj, amp1, att1);
            val = SIG0 * ssum;
        } else if (off >= 8516 && off < 8548) {             // TSC: conv2 src-transform of const h1 (nodes 0..2)
            const int fcol = off - 8516;
            const float* Wp2 = W_pre2 + i * 2176;
            float acc = 0.f;
            for (int k = 0; k < 32; ++k) {
                float ssum = 0.f;
                for (int jj = 0; jj < 32; ++jj) ssum += coef3(W1, 96 + jj, k, amp1, att1);
                const float h1c = fmaxf(b_post1[i * 32 + k] + SIG0 * ssum, 0.f);
                acc = fmaf(h1c, Wp2[(32 + k) * 32 + fcol], acc);
            }
            val = acc;
        }
        ws[WS_TAB + idx] = val;
    }
    if (t0 < 40) ws[t0] = 0.f;                              // gacc zero
    if (t0 >= 40 && t0 < 43) {                              // const-node sigmoid per intervention
        const int i = t0 - 40;
        const float* W2 = W_post2 + i * 384;
        float ssum = 0.f;
        for (int jj = 0; jj < 32; ++jj) ssum += coef3s(W2, 96 + jj, amp1, att1);
        ws[40 + i] = 1.f / (1.f + expf(-(b_post2[i] + SIG0 * ssum)));
    }
}

// ---- per-node transform, degree-pruned. dst waves (ty=0): nodes 3..10 only (8/sample).
// src waves (ty=1): conv1 nodes 0..9 (10); conv2 nodes 3..9 (7) + const TS copy for 0..2.
template<int PASS>
static __device__ __forceinline__ void conv_T(float* lds, const float* wl, int nsamp, int w, int lane,
                                              int hoff, const float* __restrict__ Wp,
                                              const float* __restrict__ bp)
{
    const int ty = w & 1;
    const int f0 = (w >> 1) * 8;
    int s, n, tasks;
    if (ty == 0)            { tasks = nsamp * 8;  s = lane >> 3;  n = 3 + (lane & 7); }
    else if (PASS == 0)     { tasks = nsamp * 10; s = lane / 10;  n = lane % 10; }
    else                    { tasks = nsamp * 7;  s = lane / 7;   n = 3 + lane % 7; }
    const bool act = lane < tasks;
    if (!act) { s = 0; n = 3; }
    const float* Hrow = lds + s * SSTRIDE + hoff + n * 36;
    const float* wbase = Wp + ty * 32 * 32 + f0;        // wave-uniform -> s_load
    float acc[8];
#pragma unroll
    for (int f = 0; f < 8; f++) acc[f] = ty ? 0.f : bp[f0 + f];
#pragma unroll
    for (int kq = 0; kq < 8; kq++) {
        float4 a = *(const float4*)(Hrow + kq * 4);
#pragma unroll
        for (int kk = 0; kk < 4; kk++) {
            float av = (kk == 0) ? a.x : (kk == 1) ? a.y : (kk == 2) ? a.z : a.w;
            const float* wr = wbase + (kq * 4 + kk) * 32;
#pragma unroll
            for (int f = 0; f < 8; f++) acc[f] = fmaf(av, wr[f], acc[f]);
        }
    }
    float* T = lds + s * SSTRIDE + (ty ? OFF_TS : OFF_TD) + n * 36 + f0;
    if (act) {
        *(float4*)(T + 0) = make_float4(acc[0], acc[1], acc[2], acc[3]);
        *(float4*)(T + 4) = make_float4(acc[4], acc[5], acc[6], acc[7]);
    }
    if (PASS == 1 && ty == 1) {                         // const TS rows (nodes 0..2 share one vector)
        if (lane < nsamp * 3) {
            const int cs = lane / 3, cn = lane % 3;
            float* Tc = lds + cs * SSTRIDE + OFF_TS + cn * 36 + f0;
            *(float4*)(Tc)     = *(const float4*)(wl + LW_TSC + f0);
            *(float4*)(Tc + 4) = *(const float4*)(wl + LW_TSC + f0 + 4);
        }
    }
}

// ---- fused message+aggregate (r7 form). wave = node class (0..5 deg2, 6 node4, 7 node10).
// CONV2=0: compute agg in regs, barrier, store AGG (AGG aliases TD/TS -> barrier required).
// CONV2=1: dot agg with folded post2 vector, shfl-reduce, sigmoid, LDS-atomic pacc.
template<int CONV2>
static __device__ __forceinline__ void fused_conv(float* lds, const float* wl, int nsamp,
                                                  int w, int lane, float b2, float* pacc)
{
    const bool act = lane < nsamp * 8;
    const int l = act ? lane : 0;
    const int s = l >> 3, q = l & 7, f = q * 4;
    float* S = lds + s * SSTRIDE;
    const float* WE = wl + (CONV2 ? LW_EA2 : LW_EA1) + f;
    const float4 w0 = *(const float4*)(WE);
    const float4 w1 = *(const float4*)(WE + 32);
    const float4 w2 = *(const float4*)(WE + 64);
    const float4 w3 = *(const float4*)(WE + 96);

    float4 r0 = make_float4(0.f,0.f,0.f,0.f), r1 = r0, r2 = r0, r3 = r0;
    float u = 0.f;

    if (w < 6) {                                           // deg-2 node C1N[w]
        const int n = C1N[w];
        float4 base = *(const float4*)(S + OFF_TD + n * 36 + f);
        float4 ma, mb;
        MSG(C1EA[w], ma);
        MSG(C1EB[w], mb);
        r0.x = (ma.x + mb.x) * 0.5f; r0.y = (ma.y + mb.y) * 0.5f;
        r0.z = (ma.z + mb.z) * 0.5f; r0.w = (ma.w + mb.w) * 0.5f;
        r1.x = fminf(ma.x, mb.x); r1.y = fminf(ma.y, mb.y);
        r1.z = fminf(ma.z, mb.z); r1.w = fminf(ma.w, mb.w);
        float4 msq;
        msq.x = fmaf(mb.x, mb.x, ma.x * ma.x) * 0.5f;
        msq.y = fmaf(mb.y, mb.y, ma.y * ma.y) * 0.5f;
        msq.z = fmaf(mb.z, mb.z, ma.z * ma.z) * 0.5f;
        msq.w = fmaf(mb.w, mb.w, ma.w * ma.w) * 0.5f;
        r2.x = sqrtf(fmaxf(msq.x - r0.x * r0.x, 0.f) + 1e-5f);
        r2.y = sqrtf(fmaxf(msq.y - r0.y * r0.y, 0.f) + 1e-5f);
        r2.z = sqrtf(fmaxf(msq.z - r0.z * r0.z, 0.f) + 1e-5f);
        r2.w = sqrtf(fmaxf(msq.w - r0.w * r0.w, 0.f) + 1e-5f);
        if (CONV2) {
            const float* V = wl + LW_V1C1 + f;
            const float4 v0 = *(const float4*)(V);
            const float4 v1 = *(const float4*)(V + 32);
            const float4 v2 = *(const float4*)(V + 64);
            u = fmaf(r0.x, v0.x, fmaf(r0.y, v0.y, fmaf(r0.z, v0.z, r0.w * v0.w)));
            u = fmaf(r1.x, v1.x, fmaf(r1.y, v1.y, fmaf(r1.z, v1.z, fmaf(r1.w, v1.w, u))));
            u = fmaf(r2.x, v2.x, fmaf(r2.y, v2.y, fmaf(r2.z, v2.z, fmaf(r2.w, v2.w, u))));
        }
    } else if (w == 6) {                                   // node4 (deg-1): agg = message
        float4 base = *(const float4*)(S + OFF_TD + 4 * 36 + f);
        float4 m;
        MSG(1, m);
        r0 = m;
        if (CONV2) {
            const float4 v0 = *(const float4*)(wl + LW_V4 + f);
            u = fmaf(m.x, v0.x, fmaf(m.y, v0.y, fmaf(m.z, v0.z, m.w * v0.w)));
        }
    } else {                                               // node10 (deg-4)
        float4 base = *(const float4*)(S + OFF_TD + 10 * 36 + f);
        float4 sum = make_float4(0.f,0.f,0.f,0.f), sq = sum;
        float4 mn = make_float4(1e30f,1e30f,1e30f,1e30f);
        float4 mx = make_float4(-1e30f,-1e30f,-1e30f,-1e30f);
#pragma unroll
        for (int e = 13; e <= 16; ++e) {
            float4 m;
            MSG(e, m);
            sum.x += m.x; sum.y += m.y; sum.z += m.z; sum.w += m.w;
            sq.x = fmaf(m.x, m.x, sq.x); sq.y = fmaf(m.y, m.y, sq.y);
            sq.z = fmaf(m.z, m.z, sq.z); sq.w = fmaf(m.w, m.w, sq.w);
            mn.x = fminf(mn.x, m.x); mn.y = fminf(mn.y, m.y); mn.z = fminf(mn.z, m.z); mn.w = fminf(mn.w, m.w);
            mx.x = fmaxf(mx.x, m.x); mx.y = fmaxf(mx.y, m.y); mx.z = fmaxf(mx.z, m.z); mx.w = fmaxf(mx.w, m.w);
        }
        r0.x = sum.x * 0.25f; r0.y = sum.y * 0.25f; r0.z = sum.z * 0.25f; r0.w = sum.w * 0.25f;
        r1 = mn; r2 = mx;
        float4 msq = make_float4(sq.x * 0.25f, sq.y * 0.25f, sq.z * 0.25f, sq.w * 0.25f);
        r3.x = sqrtf(fmaxf(msq.x - r0.x * r0.x, 0.f) + 1e-5f);
        r3.y = sqrtf(fmaxf(msq.y - r0.y * r0.y, 0.f) + 1e-5f);
        r3.z = sqrtf(fmaxf(msq.z - r0.z * r0.z, 0.f) + 1e-5f);
        r3.w = sqrtf(fmaxf(msq.w - r0.w * r0.w, 0.f) + 1e-5f);
        if (CONV2) {
            const float* V = wl + LW_V10 + f;
            const float4 v0 = *(const float4*)(V);
            const float4 v1 = *(const float4*)(V + 32);
            const float4 v2 = *(const float4*)(V + 64);
            const float4 v3 = *(const float4*)(V + 96);
            u = fmaf(r0.x, v0.x, fmaf(r0.y, v0.y, fmaf(r0.z, v0.z, r0.w * v0.w)));
            u = fmaf(r1.x, v1.x, fmaf(r1.y, v1.y, fmaf(r1.z, v1.z, fmaf(r1.w, v1.w, u))));
            u = fmaf(r2.x, v2.x, fmaf(r2.y, v2.y, fmaf(r2.z, v2.z, fmaf(r2.w, v2.w, u))));
            u = fmaf(r3.x, v3.x, fmaf(r3.y, v3.y, fmaf(r3.z, v3.z, fmaf(r3.w, v3.w, u))));
        }
    }

    if (!CONV2) {
        __syncthreads();                                   // all reads of TD/TS done before AGG overwrite
        if (act) {
            if (w < 6) {
                float* A = S + OFF_AGG + w * 100;
                *(float4*)(A + f) = r0; *(float4*)(A + 32 + f) = r1; *(float4*)(A + 64 + f) = r2;
            } else if (w == 6) {
                *(float4*)(S + OFF_AGG + OFF_A4 + f) = r0;
            } else {
                float* A = S + OFF_AGG + OFF_A10;
                *(float4*)(A + f) = r0; *(float4*)(A + 32 + f) = r1;
                *(float4*)(A + 64 + f) = r2; *(float4*)(A + 96 + f) = r3;
            }
        }
    } else {
        u += __shfl_xor(u, 1);
        u += __shfl_xor(u, 2);
        u += __shfl_xor(u, 4);
        if (act && q == 0) {
            const float extra = (w == 6) ? wl[LW_C42] : 0.f;
            const int node = (w < 6) ? C1N[w] : (w == 6 ? 4 : 10);
            const float p = 1.f / (1.f + expf(-(u + b2 + extra)));
            atomicAdd(pacc + node, p);
        }
    }
}

// ---- post1: waves 0..5 class1 (weights LDS). SPILL FIX (r13 post-mortem): the LDS-read
// FMA16 loop at unroll-2 is the 132MB spiller -- compiler hoists ds_reads, ballooning
// live ranges past cap 64. unroll 1 shrinks the hoisting window. Global paths (waves
// 6/7) keep unroll 2: proven spill-free in r12.
static __device__ __forceinline__ void post1_new(float* lds, const float* wl, int nsamp, int w, int lane,
                                                 const float* __restrict__ tabg)
{
    const bool act = lane < nsamp * 8;
    const int l = act ? lane : 0;
    const int s = l >> 3, q = l & 7;
    if (w < 6) {
        const float* A = lds + s * SSTRIDE + OFF_AGG + w * 100;
        const float* W = wl + LW_WC1 + q * 4;
        float4 u = make_float4(0.f,0.f,0.f,0.f);
#pragma unroll 1
        for (int jq = 0; jq < 24; ++jq) {
            float4 a = *(const float4*)(A + jq * 4);
            FMA16(a, W + jq * 128, u);
        }
        if (act) {
            const float4 b = *(const float4*)(wl + LW_BP1 + q * 4);
            float4 o;
            o.x = fmaxf(u.x + b.x, 0.f); o.y = fmaxf(u.y + b.y, 0.f);
            o.z = fmaxf(u.z + b.z, 0.f); o.w = fmaxf(u.w + b.w, 0.f);
            *(float4*)(lds + s * SSTRIDE + OFF_H1 + C1N[w] * 36 + q * 4) = o;
        }
    } else if (w == 7) {
        const float* A = lds + s * SSTRIDE + OFF_AGG + OFF_A10;
        const float* W = tabg + G_W10 + q * 4;
        float4 u = make_float4(0.f,0.f,0.f,0.f);
#pragma unroll 2
        for (int jq = 0; jq < 32; ++jq) {
            float4 a = *(const float4*)(A + jq * 4);
            FMA16(a, W + jq * 128, u);
        }
        if (act) {
            const float4 b = *(const float4*)(wl + LW_BP1 + q * 4);
            float4 o;
            o.x = fmaxf(u.x + b.x, 0.f); o.y = fmaxf(u.y + b.y, 0.f);
            o.z = fmaxf(u.z + b.z, 0.f); o.w = fmaxf(u.w + b.w, 0.f);
            *(float4*)(lds + s * SSTRIDE + OFF_H1 + 10 * 36 + q * 4) = o;
        }
    } else {
        const float* A = lds + s * SSTRIDE + OFF_AGG + OFF_A4;
        const float* W = tabg + G_W4 + q * 4;
        float4 u = make_float4(0.f,0.f,0.f,0.f);
#pragma unroll 2
        for (int jq = 0; jq < 8; ++jq) {
            float4 a = *(const float4*)(A + jq * 4);
            FMA16(a, W + jq * 128, u);
        }
        if (act) {
            const float4 b = *(const float4*)(wl + LW_B4 + q * 4);   // bias incl sigma0*std-colsum
            float4 o;
            o.x = fmaxf(u.x + b.x, 0.f); o.y = fmaxf(u.y + b.y, 0.f);
            o.z = fmaxf(u.z + b.z, 0.f); o.w = fmaxf(u.w + b.w, 0.f);
            *(float4*)(lds + s * SSTRIDE + OFF_H1 + 4 * 36 + q * 4) = o;
        }
    }
}

// Occupancy law (r2-r13): waves/SIMD = floor(256/VGPR); cap 64 (arg=4) -> 2 blocks/CU.
// Spill isolated to post1's LDS FMA16 loop (r11/r13 spill 132MB with it, r12 without it
// 5MB). EAT reverted: it cost +9us at equal config (r13 vs r11).
extern "C" __global__ void __launch_bounds__(TPB, 4)
pna_main(const float* __restrict__ x_input, const float* __restrict__ edge_attr,
         const float* __restrict__ W_emb,  const float* __restrict__ b_emb,
         const float* __restrict__ W_pre1, const float* __restrict__ b_pre1,
         const float* __restrict__ b_post1,
         const float* __restrict__ W_pre2, const float* __restrict__ b_pre2,
         const float* __restrict__ b_post2,
         const float* __restrict__ wstab,  float* __restrict__ gacc)
{
    extern __shared__ float lds[];
    const int tid = threadIdx.x;
    const int w = __builtin_amdgcn_readfirstlane(tid >> 6);
    const int lane = tid & 63;
    const int s0 = blockIdx.x * SB;
    const int nsamp = min(SB, B_TOT - s0);
    float* wl = lds + WLDS;
    float* pacc = lds + OFF_PACC;

    if (tid < 16) pacc[tid] = 0.f;

    for (int t = tid; t < nsamp * 68; t += TPB)
        lds[(t / 68) * SSTRIDE + OFF_EA + (t % 68)] = edge_attr[(size_t)s0 * 68 + t];

    for (int t = tid; t < nsamp * 352; t += TPB) {
        const int s = t / 352, r = t % 352, n = r >> 5, f = r & 31;
        const float* Xs = x_input + (size_t)(s0 + s) * 44 + n * 4;
        const float* We = W_emb + (n * 4) * 32 + f;
        float v = b_emb[n * 32 + f];
        v = fmaf(Xs[0], We[0],  v);
        v = fmaf(Xs[1], We[32], v);
        v = fmaf(Xs[2], We[64], v);
        v = fmaf(Xs[3], We[96], v);
        lds[s * SSTRIDE + OFF_H + n * 36 + f] = fmaxf(v, 0.f);
    }
    __syncthreads();

    for (int i = 0; i < 3; i++) {
        const float* tab = wstab + i * WTAB;
        // stage class1 post1 block (3072 floats) + small tables -> LDS
        for (int t = tid; t < 768; t += TPB)
            ((float4*)(wl + LW_WC1))[t] = ((const float4*)(tab + G_WC1))[t];
        if (tid < 89)       ((float4*)wl)[tid] = ((const float4*)(tab + G_SM))[tid];
        else if (tid < 97)  ((float4*)(wl + LW_BP1))[tid - 89] = ((const float4*)(b_post1 + i * 32))[tid - 89];
        else if (tid < 129) ((float4*)(wl + LW_EA1))[tid - 97] = ((const float4*)(W_pre1 + i * 2176 + 2048))[tid - 97];
        else if (tid < 161) ((float4*)(wl + LW_EA2))[tid - 129] = ((const float4*)(W_pre2 + i * 2176 + 2048))[tid - 129];

        conv_T<0>(lds, wl, nsamp, w, lane, OFF_H, W_pre1 + i * 2176, b_pre1 + i * 32);
        __syncthreads();                                   // B1: T ready (+ wl staged)
        fused_conv<0>(lds, wl, nsamp, w, lane, 0.f, pacc); // compute, internal barrier, store AGG
        __syncthreads();                                   // B2: AGG ready
        post1_new(lds, wl, nsamp, w, lane, tab);
        __syncthreads();                                   // B3: H1 ready
        conv_T<1>(lds, wl, nsamp, w, lane, OFF_H1, W_pre2 + i * 2176, b_pre2 + i * 32);
        __syncthreads();                                   // B4: T2 ready (incl const TS rows)
        fused_conv<1>(lds, wl, nsamp, w, lane, b_post2[i], pacc);
        __syncthreads();                                   // B5: pacc complete
        if (tid < 11) {
            atomicAdd(gacc + i * 11 + tid, pacc[tid]);
            pacc[tid] = 0.f;
        }
    }
}

extern "C" __global__ void pna_final(const float* __restrict__ ws,
                                     const float* __restrict__ W_fc,
                                     const float* __restrict__ b_fc,
                                     float* __restrict__ out)
{
    const int i = threadIdx.x;
    if (i < 3) {
        float acc = 0.f;
        for (int n = 0; n < 11; n++)
            acc = fmaf(ws[i * 11 + n] * (1.f / 16384.f), W_fc[i * 11 + n], acc);
        const float pc = ws[40 + i];
        const float wsum = W_fc[i * 11 + 0] + W_fc[i * 11 + 1] + W_fc[i * 11 + 2];
        out[i] = acc + pc * wsum + b_fc[i];
    }
}

extern "C" void kernel_launch(void* const* d_in, const int* in_sizes, int n_in,
                              void* d_out, int out_size, void* d_ws, size_t ws_size,
                              hipStream_t stream)
{
    (void)in_sizes; (void)n_in; (void)out_size; (void)ws_size;
    const float* x_input   = (const float*)d_in[0];
    const float* edge_attr = (const float*)d_in[1];
    const float* W_emb     = (const float*)d_in[2];
    const float* b_emb     = (const float*)d_in[3];
    const float* W_pre1    = (const float*)d_in[4];
    const float* b_pre1    = (const float*)d_in[5];
    const float* W_post1   = (const float*)d_in[6];
    const float* b_post1   = (const float*)d_in[7];
    const float* W_pre2    = (const float*)d_in[8];
    const float* b_pre2    = (const float*)d_in[9];
    const float* W_post2   = (const float*)d_in[10];
    const float* b_post2   = (const float*)d_in[11];
    const float* W_fc      = (const float*)d_in[12];
    const float* b_fc      = (const float*)d_in[13];
    float* ws  = (float*)d_ws;
    float* out = (float*)d_out;

    hipLaunchKernelGGL(pna_fold, dim3(64), dim3(512), 0, stream,
                       W_post1, b_post1, W_post2, b_post2, W_pre2, ws);
    const int grid = (B_TOT + SB - 1) / SB;
    const size_t shmem = (size_t)LDS_FLOATS * sizeof(float);
    hipLaunchKernelGGL(pna_main, dim3(grid), dim3(TPB), shmem, stream,
                       x_input, edge_attr, W_emb, b_emb,
                       W_pre1, b_pre1, b_post1,
                       W_pre2, b_pre2, b_post2,
                       ws + WS_TAB, ws);
    hipLaunchKernelGGL(pna_final, dim3(1), dim3(64), 0, stream, ws, W_fc, b_fc, out);
}

// Round 16
// 322.004 us; speedup vs baseline: 1.2752x; 1.0092x over previous
//
#include <hip/hip_runtime.h>
#include <math.h>

#define B_TOT   16384
#define SB      6              // 6 samples/block: conv1-src tasks = 60 <= 64 lanes (binding)
#define TPB     512

// ---- per-sample LDS layout (floats), COMPACT (r13-verified): TD holds dst nodes 3..10 only
#define SSTRIDE 1596
#define OFF_H   0              // 11*36 = 396, lives whole kernel
#define OFF_EA  396            // 68
#define OFF_H1  464            // 396, post1 out -> conv_T2 in
#define OFF_AGG 860            // conv region: TD(288)+TS(396)=684 during conv; AGG(736) after
#define OFF_TD  860            // COMPACT: dst nodes 3..10 at (n-3)*36, 288 floats
#define OFF_TS  1148           // full 11-node src layout, 396 floats
#define OFF_A4  576            // node4 agg offset within AGG (after 6*96 c1 blocks)
#define OFF_A10 608            // node10 agg offset within AGG (608..736)
#define WLDS    (SB * SSTRIDE) // 9576

// ---- LDS weight-table (wl) layout (mirrors ws SM block order)
#define LW_B4   0              // node4 post1 bias incl sigma0*std-colsum (32)
#define LW_H1C  32             // const h1 row for nodes 0..2 (32) [table only]
#define LW_V1C1 64             // class1 post2 vector (96)
#define LW_V10  160            // node10 post2 vector (128)
#define LW_V4   288            // node4 post2 vector (32)
#define LW_C42  320            // node4 post2 sigma0 const (1) + 3 pad
#define LW_TSC  324            // const conv2 src-transform row (nodes 0..2 share it) (32)
#define LW_BP1  356            // b_post1 row (32)
#define LW_EA1  388            // W_pre1 rows 64..67 (128)
#define LW_EA2  516            // W_pre2 rows 64..67 (128)
#define LW_WC1  644            // class1 post1 [96][32] (read by 6 waves) (3072)
#define LTAB    3716

#define OFF_PACC (WLDS + LTAB)
#define LDS_FLOATS (WLDS + LTAB + 16)   // 13308 floats = 53232 B -> 3 blocks/CU (160KB LDS)
#define AVG_LOG 0.9976091242438673f

// ---- ws per-intervention folded table
#define G_WC1  0               // class1 post1 [96][32]
#define G_W10  3072            // node10 post1 [128][32] (wave 7 only, global/L1)
#define G_W4   7168            // node4 post1 [32][32]  (wave 6 only, global/L1)
#define G_SM   8192            // small tail (356) staged to wl[0..356)
#define WTAB   8548
#define WS_TAB 64              // ws: [0..39] gacc, [40..42] const-node sigmoid

__constant__ int C_ESRC[17] = {0,0,1,1,2,0,3,4,5,6,7,2,8,3,6,9,1};
__constant__ int C1EA[6] = {0,3,5,7,9,11};     // first in-edge of deg-2 nodes
__constant__ int C1EB[6] = {2,4,6,8,10,12};    // second in-edge
__constant__ int C1N[6]  = {3,5,6,7,8,9};      // deg-2 node ids

#define FMA16(a, wb, u) do { \
    float4 w0_ = *(const float4*)(wb); \
    float4 w1_ = *(const float4*)((wb) + 32); \
    float4 w2_ = *(const float4*)((wb) + 64); \
    float4 w3_ = *(const float4*)((wb) + 96); \
    u.x = fmaf(a.x, w0_.x, u.x); u.y = fmaf(a.x, w0_.y, u.y); u.z = fmaf(a.x, w0_.z, u.z); u.w = fmaf(a.x, w0_.w, u.w); \
    u.x = fmaf(a.y, w1_.x, u.x); u.y = fmaf(a.y, w1_.y, u.y); u.z = fmaf(a.y, w1_.z, u.z); u.w = fmaf(a.y, w1_.w, u.w); \
    u.x = fmaf(a.z, w2_.x, u.x); u.y = fmaf(a.z, w2_.y, u.y); u.z = fmaf(a.z, w2_.z, u.z); u.w = fmaf(a.z, w2_.w, u.w); \
    u.x = fmaf(a.w, w3_.x, u.x); u.y = fmaf(a.w, w3_.y, u.y); u.z = fmaf(a.w, w3_.z, u.z); u.w = fmaf(a.w, w3_.w, u.w); \
} while (0)

// message for edge e_: m = relu(TDquad(base) + TSquad(src) + ea@Wrows64..67)  [r7 form]
#define MSG(e_, m_) do { \
    const float4 ev_ = *(const float4*)(S + OFF_EA + (e_) * 4); \
    const float4 ts_ = *(const float4*)(S + OFF_TS + C_ESRC[(e_)] * 36 + f); \
    m_.x = base.x + ts_.x; m_.y = base.y + ts_.y; m_.z = base.z + ts_.z; m_.w = base.w + ts_.w; \
    m_.x = fmaf(ev_.x, w0.x, m_.x); m_.y = fmaf(ev_.x, w0.y, m_.y); m_.z = fmaf(ev_.x, w0.z, m_.z); m_.w = fmaf(ev_.x, w0.w, m_.w); \
    m_.x = fmaf(ev_.y, w1.x, m_.x); m_.y = fmaf(ev_.y, w1.y, m_.y); m_.z = fmaf(ev_.y, w1.z, m_.z); m_.w = fmaf(ev_.y, w1.w, m_.w); \
    m_.x = fmaf(ev_.z, w2.x, m_.x); m_.y = fmaf(ev_.z, w2.y, m_.y); m_.z = fmaf(ev_.z, w2.z, m_.z); m_.w = fmaf(ev_.z, w2.w, m_.w); \
    m_.x = fmaf(ev_.w, w3.x, m_.x); m_.y = fmaf(ev_.w, w3.y, m_.y); m_.z = fmaf(ev_.w, w3.z, m_.z); m_.w = fmaf(ev_.w, w3.w, m_.w); \
    m_.x = fmaxf(m_.x, 0.f); m_.y = fmaxf(m_.y, 0.f); m_.z = fmaxf(m_.z, 0.f); m_.w = fmaxf(m_.w, 0.f); \
} while (0)

static __device__ __forceinline__ float coef3(const float* __restrict__ W1, int r, int fcol, float amp, float att)
{
    return W1[r * 32 + fcol] + amp * W1[(128 + r) * 32 + fcol] + att * W1[(256 + r) * 32 + fcol];
}
static __device__ __forceinline__ float coef3s(const float* __restrict__ W2, int r, float amp, float att)
{
    return W2[r] + amp * W2[128 + r] + att * W2[256 + r];
}

// ---- one-shot fold: amp/att per degree class + graph-structure identities
extern "C" __global__ void pna_fold(const float* __restrict__ W_post1, const float* __restrict__ b_post1,
                                    const float* __restrict__ W_post2, const float* __restrict__ b_post2,
                                    const float* __restrict__ W_pre2,  float* __restrict__ ws)
{
    const int t0 = blockIdx.x * blockDim.x + threadIdx.x;
    const int NT = gridDim.x * blockDim.x;
    const float l1 = log1pf(1.f), l2 = log1pf(2.f), l4 = log1pf(4.f);
    const float amp1 = l1 / AVG_LOG, att1 = AVG_LOG / l1;
    const float amp2 = l2 / AVG_LOG, att2 = AVG_LOG / l2;
    const float amp4 = l4 / AVG_LOG, att4 = AVG_LOG / l4;
    const float SIG0 = 0.0031622776601683794f;   // sqrt(1e-5)

    for (int idx = t0; idx < 3 * WTAB; idx += NT) {
        const int i = idx / WTAB, off = idx % WTAB;
        const float* W1 = W_post1 + i * 384 * 32;
        const float* W2 = W_post2 + i * 384;
        float val = 0.f;
        if (off < 3072) {                                   // WC1: deg-2 fold (mx = 2*mean - mn)
            const int j = off >> 5, fcol = off & 31, sub = j >> 5, jj = j & 31;
            if (sub == 0)      val = coef3(W1, jj, fcol, amp2, att2) + 2.f * coef3(W1, 64 + jj, fcol, amp2, att2);
            else if (sub == 1) val = coef3(W1, 32 + jj, fcol, amp2, att2) - coef3(W1, 64 + jj, fcol, amp2, att2);
            else               val = coef3(W1, 96 + jj, fcol, amp2, att2);
        } else if (off < 7168) {                            // W10: full [mean|mn|mx|std] rows
            const int rr = off - 3072;
            val = coef3(W1, rr >> 5, rr & 31, amp4, att4);
        } else if (off < 8192) {                            // W4: Wm+Wmn+Wmx fold
            const int rr = off - 7168, jj = rr >> 5, fcol = rr & 31;
            val = coef3(W1, jj, fcol, amp1, att1) + coef3(W1, 32 + jj, fcol, amp1, att1)
                + coef3(W1, 64 + jj, fcol, amp1, att1);
        } else if (off < 8224) {                            // B4
            const int fcol = off - 8192;
            float ssum = 0.f;
            for (int jj = 0; jj < 32; ++jj) ssum += coef3(W1, 96 + jj, fcol, amp1, att1);
            val = b_post1[i * 32 + fcol] + SIG0 * ssum;
        } else if (off < 8256) {                            // H1C (const rows, nodes 0..2)
            const int fcol = off - 8224;
            float ssum = 0.f;
            for (int jj = 0; jj < 32; ++jj) ssum += coef3(W1, 96 + jj, fcol, amp1, att1);
            val = fmaxf(b_post1[i * 32 + fcol] + SIG0 * ssum, 0.f);
        } else if (off < 8352) {                            // V1C1
            const int j = off - 8256, sub = j >> 5, jj = j & 31;
            if (sub == 0)      val = coef3s(W2, jj, amp2, att2) + 2.f * coef3s(W2, 64 + jj, amp2, att2);
            else if (sub == 1) val = coef3s(W2, 32 + jj, amp2, att2) - coef3s(W2, 64 + jj, amp2, att2);
            else               val = coef3s(W2, 96 + jj, amp2, att2);
        } else if (off < 8480) {                            // V10
            val = coef3s(W2, off - 8352, amp4, att4);
        } else if (off < 8512) {                            // V4
            const int jj = off - 8480;
            val = coef3s(W2, jj, amp1, att1) + coef3s(W2, 32 + jj, amp1, att1) + coef3s(W2, 64 + jj, amp1, att1);
        } else if (off == 8512) {                           // C42
            float ssum = 0.f;
            for (int jj = 0; jj < 32; ++jj) ssum += coef3s(W2, 96 + jj, amp1, att1);
            val = SIG0 * ssum;
        } else if (off >= 8516 && off < 8548) {             // TSC: conv2 src-transform of const h1 (nodes 0..2)
            const int fcol = off - 8516;
            const float* Wp2 = W_pre2 + i * 2176;
            float acc = 0.f;
            for (int k = 0; k < 32; ++k) {
                float ssum = 0.f;
                for (int jj = 0; jj < 32; ++jj) ssum += coef3(W1, 96 + jj, k, amp1, att1);
                const float h1c = fmaxf(b_post1[i * 32 + k] + SIG0 * ssum, 0.f);
                acc = fmaf(h1c, Wp2[(32 + k) * 32 + fcol], acc);
            }
            val = acc;
        }
        ws[WS_TAB + idx] = val;
    }
    if (t0 < 40) ws[t0] = 0.f;                              // gacc zero
    if (t0 >= 40 && t0 < 43) {                              // const-node sigmoid per intervention
        const int i = t0 - 40;
        const float* W2 = W_post2 + i * 384;
        float ssum = 0.f;
        for (int jj = 0; jj < 32; ++jj) ssum += coef3s(W2, 96 + jj, amp1, att1);
        ws[40 + i] = 1.f / (1.f + expf(-(b_post2[i] + SIG0 * ssum)));
    }
}

// ---- per-node transform, degree-pruned. dst waves (ty=0): nodes 3..10 -> COMPACT TD.
// src waves (ty=1): conv1 nodes 0..9 (10); conv2 nodes 3..9 (7) + const TS copy for 0..2.
template<int PASS>
static __device__ __forceinline__ void conv_T(float* lds, const float* wl, int nsamp, int w, int lane,
                                              int hoff, const float* __restrict__ Wp,
                                              const float* __restrict__ bp)
{
    const int ty = w & 1;
    const int f0 = (w >> 1) * 8;
    int s, n, tasks;
    if (ty == 0)            { tasks = nsamp * 8;  s = lane >> 3;  n = 3 + (lane & 7); }
    else if (PASS == 0)     { tasks = nsamp * 10; s = lane / 10;  n = lane % 10; }
    else                    { tasks = nsamp * 7;  s = lane / 7;   n = 3 + lane % 7; }
    const bool act = lane < tasks;
    if (!act) { s = 0; n = 3; }
    const float* Hrow = lds + s * SSTRIDE + hoff + n * 36;
    const float* wbase = Wp + ty * 32 * 32 + f0;        // wave-uniform -> s_load
    float acc[8];
#pragma unroll
    for (int f = 0; f < 8; f++) acc[f] = ty ? 0.f : bp[f0 + f];
#pragma unroll
    for (int kq = 0; kq < 8; kq++) {
        float4 a = *(const float4*)(Hrow + kq * 4);
#pragma unroll
        for (int kk = 0; kk < 4; kk++) {
            float av = (kk == 0) ? a.x : (kk == 1) ? a.y : (kk == 2) ? a.z : a.w;
            const float* wr = wbase + (kq * 4 + kk) * 32;
#pragma unroll
            for (int f = 0; f < 8; f++) acc[f] = fmaf(av, wr[f], acc[f]);
        }
    }
    float* T = lds + s * SSTRIDE + (ty ? (OFF_TS + n * 36) : (OFF_TD + (n - 3) * 36)) + f0;
    if (act) {
        *(float4*)(T + 0) = make_float4(acc[0], acc[1], acc[2], acc[3]);
        *(float4*)(T + 4) = make_float4(acc[4], acc[5], acc[6], acc[7]);
    }
    if (PASS == 1 && ty == 1) {                         // const TS rows (nodes 0..2 share one vector)
        if (lane < nsamp * 3) {
            const int cs = lane / 3, cn = lane % 3;
            float* Tc = lds + cs * SSTRIDE + OFF_TS + cn * 36 + f0;
            *(float4*)(Tc)     = *(const float4*)(wl + LW_TSC + f0);
            *(float4*)(Tc + 4) = *(const float4*)(wl + LW_TSC + f0 + 4);
        }
    }
}

// ---- fused message+aggregate (r7 form, compact TD). wave = node class (0..5 deg2, 6 node4, 7 node10).
// CONV2=0: compute agg in regs, barrier, store AGG (AGG aliases TD/TS -> barrier required).
// CONV2=1: dot agg with folded post2 vector, shfl-reduce, sigmoid, LDS-atomic pacc.
template<int CONV2>
static __device__ __forceinline__ void fused_conv(float* lds, const float* wl, int nsamp,
                                                  int w, int lane, float b2, float* pacc)
{
    const bool act = lane < nsamp * 8;
    const int l = act ? lane : 0;
    const int s = l >> 3, q = l & 7, f = q * 4;
    float* S = lds + s * SSTRIDE;
    const float* WE = wl + (CONV2 ? LW_EA2 : LW_EA1) + f;
    const float4 w0 = *(const float4*)(WE);
    const float4 w1 = *(const float4*)(WE + 32);
    const float4 w2 = *(const float4*)(WE + 64);
    const float4 w3 = *(const float4*)(WE + 96);

    float4 r0 = make_float4(0.f,0.f,0.f,0.f), r1 = r0, r2 = r0, r3 = r0;
    float u = 0.f;

    if (w < 6) {                                           // deg-2 node C1N[w]
        float4 base = *(const float4*)(S + OFF_TD + (C1N[w] - 3) * 36 + f);
        float4 ma, mb;
        MSG(C1EA[w], ma);
        MSG(C1EB[w], mb);
        r0.x = (ma.x + mb.x) * 0.5f; r0.y = (ma.y + mb.y) * 0.5f;
        r0.z = (ma.z + mb.z) * 0.5f; r0.w = (ma.w + mb.w) * 0.5f;
        r1.x = fminf(ma.x, mb.x); r1.y = fminf(ma.y, mb.y);
        r1.z = fminf(ma.z, mb.z); r1.w = fminf(ma.w, mb.w);
        float4 msq;
        msq.x = fmaf(mb.x, mb.x, ma.x * ma.x) * 0.5f;
        msq.y = fmaf(mb.y, mb.y, ma.y * ma.y) * 0.5f;
        msq.z = fmaf(mb.z, mb.z, ma.z * ma.z) * 0.5f;
        msq.w = fmaf(mb.w, mb.w, ma.w * ma.w) * 0.5f;
        r2.x = sqrtf(fmaxf(msq.x - r0.x * r0.x, 0.f) + 1e-5f);
        r2.y = sqrtf(fmaxf(msq.y - r0.y * r0.y, 0.f) + 1e-5f);
        r2.z = sqrtf(fmaxf(msq.z - r0.z * r0.z, 0.f) + 1e-5f);
        r2.w = sqrtf(fmaxf(msq.w - r0.w * r0.w, 0.f) + 1e-5f);
        if (CONV2) {
            const float* V = wl + LW_V1C1 + f;
            const float4 v0 = *(const float4*)(V);
            const float4 v1 = *(const float4*)(V + 32);
            const float4 v2 = *(const float4*)(V + 64);
            u = fmaf(r0.x, v0.x, fmaf(r0.y, v0.y, fmaf(r0.z, v0.z, r0.w * v0.w)));
            u = fmaf(r1.x, v1.x, fmaf(r1.y, v1.y, fmaf(r1.z, v1.z, fmaf(r1.w, v1.w, u))));
            u = fmaf(r2.x, v2.x, fmaf(r2.y, v2.y, fmaf(r2.z, v2.z, fmaf(r2.w, v2.w, u))));
        }
    } else if (w == 6) {                                   // node4 (deg-1): agg = message
        float4 base = *(const float4*)(S + OFF_TD + 1 * 36 + f);   // node4 -> compact idx 1
        float4 m;
        MSG(1, m);
        r0 = m;
        if (CONV2) {
            const float4 v0 = *(const float4*)(wl + LW_V4 + f);
            u = fmaf(m.x, v0.x, fmaf(m.y, v0.y, fmaf(m.z, v0.z, m.w * v0.w)));
        }
    } else {                                               // node10 (deg-4), edges 13..16
        float4 base = *(const float4*)(S + OFF_TD + 7 * 36 + f);   // node10 -> compact idx 7
        float4 sum = make_float4(0.f,0.f,0.f,0.f), sq = sum;
        float4 mn = make_float4(1e30f,1e30f,1e30f,1e30f);
        float4 mx = make_float4(-1e30f,-1e30f,-1e30f,-1e30f);
#pragma unroll
        for (int e = 13; e <= 16; ++e) {
            float4 m;
            MSG(e, m);
            sum.x += m.x; sum.y += m.y; sum.z += m.z; sum.w += m.w;
            sq.x = fmaf(m.x, m.x, sq.x); sq.y = fmaf(m.y, m.y, sq.y);
            sq.z = fmaf(m.z, m.z, sq.z); sq.w = fmaf(m.w, m.w, sq.w);
            mn.x = fminf(mn.x, m.x); mn.y = fminf(mn.y, m.y); mn.z = fminf(mn.z, m.z); mn.w = fminf(mn.w, m.w);
            mx.x = fmaxf(mx.x, m.x); mx.y = fmaxf(mx.y, m.y); mx.z = fmaxf(mx.z, m.z); mx.w = fmaxf(mx.w, m.w);
        }
        r0.x = sum.x * 0.25f; r0.y = sum.y * 0.25f; r0.z = sum.z * 0.25f; r0.w = sum.w * 0.25f;
        r1 = mn; r2 = mx;
        float4 msq = make_float4(sq.x * 0.25f, sq.y * 0.25f, sq.z * 0.25f, sq.w * 0.25f);
        r3.x = sqrtf(fmaxf(msq.x - r0.x * r0.x, 0.f) + 1e-5f);
        r3.y = sqrtf(fmaxf(msq.y - r0.y * r0.y, 0.f) + 1e-5f);
        r3.z = sqrtf(fmaxf(msq.z - r0.z * r0.z, 0.f) + 1e-5f);
        r3.w = sqrtf(fmaxf(msq.w - r0.w * r0.w, 0.f) + 1e-5f);
        if (CONV2) {
            const float* V = wl + LW_V10 + f;
            const float4 v0 = *(const float4*)(V);
            const float4 v1 = *(const float4*)(V + 32);
            const float4 v2 = *(const float4*)(V + 64);
            const float4 v3 = *(const float4*)(V + 96);
            u = fmaf(r0.x, v0.x, fmaf(r0.y, v0.y, fmaf(r0.z, v0.z, r0.w * v0.w)));
            u = fmaf(r1.x, v1.x, fmaf(r1.y, v1.y, fmaf(r1.z, v1.z, fmaf(r1.w, v1.w, u))));
            u = fmaf(r2.x, v2.x, fmaf(r2.y, v2.y, fmaf(r2.z, v2.z, fmaf(r2.w, v2.w, u))));
            u = fmaf(r3.x, v3.x, fmaf(r3.y, v3.y, fmaf(r3.z, v3.z, fmaf(r3.w, v3.w, u))));
        }
    }

    if (!CONV2) {
        __syncthreads();                                   // all reads of TD/TS done before AGG overwrite
        if (act) {
            if (w < 6) {
                float* A = S + OFF_AGG + w * 96;
                *(float4*)(A + f) = r0; *(float4*)(A + 32 + f) = r1; *(float4*)(A + 64 + f) = r2;
            } else if (w == 6) {
                *(float4*)(S + OFF_AGG + OFF_A4 + f) = r0;
            } else {
                float* A = S + OFF_AGG + OFF_A10;
                *(float4*)(A + f) = r0; *(float4*)(A + 32 + f) = r1;
                *(float4*)(A + 64 + f) = r2; *(float4*)(A + 96 + f) = r3;
            }
        }
    } else {
        u += __shfl_xor(u, 1);
        u += __shfl_xor(u, 2);
        u += __shfl_xor(u, 4);
        if (act && q == 0) {
            const float extra = (w == 6) ? wl[LW_C42] : 0.f;
            const int node = (w < 6) ? C1N[w] : (w == 6 ? 4 : 10);
            const float p = 1.f / (1.f + expf(-(u + b2 + extra)));
            atomicAdd(pacc + node, p);
        }
    }
}

// ---- post1: waves 0..5 class1 (weights LDS, unroll-1 = r15 spill fix), wave 6 node4
//      (global, unroll-2), wave 7 node10 (global, unroll-2, L1-resident).
static __device__ __forceinline__ void post1_new(float* lds, const float* wl, int nsamp, int w, int lane,
                                                 const float* __restrict__ tabg)
{
    const bool act = lane < nsamp * 8;
    const int l = act ? lane : 0;
    const int s = l >> 3, q = l & 7;
    if (w < 6) {
        const float* A = lds + s * SSTRIDE + OFF_AGG + w * 96;
        const float* W = wl + LW_WC1 + q * 4;
        float4 u = make_float4(0.f,0.f,0.f,0.f);
#pragma unroll 1
        for (int jq = 0; jq < 24; ++jq) {
            float4 a = *(const float4*)(A + jq * 4);
            FMA16(a, W + jq * 128, u);
        }
        if (act) {
            const float4 b = *(const float4*)(wl + LW_BP1 + q * 4);
            float4 o;
            o.x = fmaxf(u.x + b.x, 0.f); o.y = fmaxf(u.y + b.y, 0.f);
            o.z = fmaxf(u.z + b.z, 0.f); o.w = fmaxf(u.w + b.w, 0.f);
            *(float4*)(lds + s * SSTRIDE + OFF_H1 + C1N[w] * 36 + q * 4) = o;
        }
    } else if (w == 7) {
        const float* A = lds + s * SSTRIDE + OFF_AGG + OFF_A10;
        const float* W = tabg + G_W10 + q * 4;
        float4 u = make_float4(0.f,0.f,0.f,0.f);
#pragma unroll 2
        for (int jq = 0; jq < 32; ++jq) {
            float4 a = *(const float4*)(A + jq * 4);
            FMA16(a, W + jq * 128, u);
        }
        if (act) {
            const float4 b = *(const float4*)(wl + LW_BP1 + q * 4);
            float4 o;
            o.x = fmaxf(u.x + b.x, 0.f); o.y = fmaxf(u.y + b.y, 0.f);
            o.z = fmaxf(u.z + b.z, 0.f); o.w = fmaxf(u.w + b.w, 0.f);
            *(float4*)(lds + s * SSTRIDE + OFF_H1 + 10 * 36 + q * 4) = o;
        }
    } else {
        const float* A = lds + s * SSTRIDE + OFF_AGG + OFF_A4;
        const float* W = tabg + G_W4 + q * 4;
        float4 u = make_float4(0.f,0.f,0.f,0.f);
#pragma unroll 2
        for (int jq = 0; jq < 8; ++jq) {
            float4 a = *(const float4*)(A + jq * 4);
            FMA16(a, W + jq * 128, u);
        }
        if (act) {
            const float4 b = *(const float4*)(wl + LW_B4 + q * 4);   // bias incl sigma0*std-colsum
            float4 o;
            o.x = fmaxf(u.x + b.x, 0.f); o.y = fmaxf(u.y + b.y, 0.f);
            o.z = fmaxf(u.z + b.z, 0.f); o.w = fmaxf(u.w + b.w, 0.f);
            *(float4*)(lds + s * SSTRIDE + OFF_H1 + 4 * 36 + q * 4) = o;
        }
    }
}

// r15: spill fixed (WRITE 132->0.6MB, VGPR 56). VGPR<=64 allows 4 blocks/CU; LDS was
// the binder (54.6KB*3 > 160KB). This round: r13-verified TD/AGG compaction shrinks
// LDS to 53.2KB -> 3 blocks/CU (159.7KB <= 160KB).
extern "C" __global__ void __launch_bounds__(TPB, 4)
pna_main(const float* __restrict__ x_input, const float* __restrict__ edge_attr,
         const float* __restrict__ W_emb,  const float* __restrict__ b_emb,
         const float* __restrict__ W_pre1, const float* __restrict__ b_pre1,
         const float* __restrict__ b_post1,
         const float* __restrict__ W_pre2, const float* __restrict__ b_pre2,
         const float* __restrict__ b_post2,
         const float* __restrict__ wstab,  float* __restrict__ gacc)
{
    extern __shared__ float lds[];
    const int tid = threadIdx.x;
    const int w = __builtin_amdgcn_readfirstlane(tid >> 6);
    const int lane = tid & 63;
    const int s0 = blockIdx.x * SB;
    const int nsamp = min(SB, B_TOT - s0);
    float* wl = lds + WLDS;
    float* pacc = lds + OFF_PACC;

    if (tid < 16) pacc[tid] = 0.f;

    for (int t = tid; t < nsamp * 68; t += TPB)
        lds[(t / 68) * SSTRIDE + OFF_EA + (t % 68)] = edge_attr[(size_t)s0 * 68 + t];

    for (int t = tid; t < nsamp * 352; t += TPB) {
        const int s = t / 352, r = t % 352, n = r >> 5, f = r & 31;
        const float* Xs = x_input + (size_t)(s0 + s) * 44 + n * 4;
        const float* We = W_emb + (n * 4) * 32 + f;
        float v = b_emb[n * 32 + f];
        v = fmaf(Xs[0], We[0],  v);
        v = fmaf(Xs[1], We[32], v);
        v = fmaf(Xs[2], We[64], v);
        v = fmaf(Xs[3], We[96], v);
        lds[s * SSTRIDE + OFF_H + n * 36 + f] = fmaxf(v, 0.f);
    }
    __syncthreads();

    for (int i = 0; i < 3; i++) {
        const float* tab = wstab + i * WTAB;
        // stage class1 post1 block (3072 floats) + small tables -> LDS
        for (int t = tid; t < 768; t += TPB)
            ((float4*)(wl + LW_WC1))[t] = ((const float4*)(tab + G_WC1))[t];
        if (tid < 89)       ((float4*)wl)[tid] = ((const float4*)(tab + G_SM))[tid];
        else if (tid < 97)  ((float4*)(wl + LW_BP1))[tid - 89] = ((const float4*)(b_post1 + i * 32))[tid - 89];
        else if (tid < 129) ((float4*)(wl + LW_EA1))[tid - 97] = ((const float4*)(W_pre1 + i * 2176 + 2048))[tid - 97];
        else if (tid < 161) ((float4*)(wl + LW_EA2))[tid - 129] = ((const float4*)(W_pre2 + i * 2176 + 2048))[tid - 129];

        conv_T<0>(lds, wl, nsamp, w, lane, OFF_H, W_pre1 + i * 2176, b_pre1 + i * 32);
        __syncthreads();                                   // B1: T ready (+ wl staged)
        fused_conv<0>(lds, wl, nsamp, w, lane, 0.f, pacc); // compute, internal barrier, store AGG
        __syncthreads();                                   // B2: AGG ready
        post1_new(lds, wl, nsamp, w, lane, tab);
        __syncthreads();                                   // B3: H1 ready
        conv_T<1>(lds, wl, nsamp, w, lane, OFF_H1, W_pre2 + i * 2176, b_pre2 + i * 32);
        __syncthreads();                                   // B4: T2 ready (incl const TS rows)
        fused_conv<1>(lds, wl, nsamp, w, lane, b_post2[i], pacc);
        __syncthreads();                                   // B5: pacc complete
        if (tid < 11) {
            atomicAdd(gacc + i * 11 + tid, pacc[tid]);
            pacc[tid] = 0.f;
        }
    }
}

extern "C" __global__ void pna_final(const float* __restrict__ ws,
                                     const float* __restrict__ W_fc,
                                     const float* __restrict__ b_fc,
                                     float* __restrict__ out)
{
    const int i = threadIdx.x;
    if (i < 3) {
        float acc = 0.f;
        for (int n = 0; n < 11; n++)
            acc = fmaf(ws[i * 11 + n] * (1.f / 16384.f), W_fc[i * 11 + n], acc);
        const float pc = ws[40 + i];
        const float wsum = W_fc[i * 11 + 0] + W_fc[i * 11 + 1] + W_fc[i * 11 + 2];
        out[i] = acc + pc * wsum + b_fc[i];
    }
}

extern "C" void kernel_launch(void* const* d_in, const int* in_sizes, int n_in,
                              void* d_out, int out_size, void* d_ws, size_t ws_size,
                              hipStream_t stream)
{
    (void)in_sizes; (void)n_in; (void)out_size; (void)ws_size;
    const float* x_input   = (const float*)d_in[0];
    const float* edge_attr = (const float*)d_in[1];
    const float* W_emb     = (const float*)d_in[2];
    const float* b_emb     = (const float*)d_in[3];
    const float* W_pre1    = (const float*)d_in[4];
    const float* b_pre1    = (const float*)d_in[5];
    const float* W_post1   = (const float*)d_in[6];
    const float* b_post1   = (const float*)d_in[7];
    const float* W_pre2    = (const float*)d_in[8];
    const float* b_pre2    = (const float*)d_in[9];
    const float* W_post2   = (const float*)d_in[10];
    const float* b_post2   = (const float*)d_in[11];
    const float* W_fc      = (const float*)d_in[12];
    const float* b_fc      = (const float*)d_in[13];
    float* ws  = (float*)d_ws;
    float* out = (float*)d_out;

    hipLaunchKernelGGL(pna_fold, dim3(64), dim3(512), 0, stream,
                       W_post1, b_post1, W_post2, b_post2, W_pre2, ws);
    const int grid = (B_TOT + SB - 1) / SB;
    const size_t shmem = (size_t)LDS_FLOATS * sizeof(float);
    hipLaunchKernelGGL(pna_main, dim3(grid), dim3(TPB), shmem, stream,
                       x_input, edge_attr, W_emb, b_emb,
                       W_pre1, b_pre1, b_post1,
                       W_pre2, b_pre2, b_post2,
                       ws + WS_TAB, ws);
    hipLaunchKernelGGL(pna_final, dim3(1), dim3(64), 0, stream, ws, W_fc, b_fc, out);
}